// Round 17
// baseline (404.841 us; speedup 1.0000x reference)
//
#include <hip/hip_runtime.h>
#include <math.h>

#define BD 8
#define DD 1024
#define EE 256
#define HH 8
#define HDD 32
#define NBITS 11

typedef __attribute__((ext_vector_type(8))) short short8;
typedef __attribute__((ext_vector_type(4))) float f4;

__device__ __forceinline__ ushort f2bf(float f) {
  unsigned u = __float_as_uint(f);
  u += 0x7fffu + ((u >> 16) & 1u);
  return (ushort)(u >> 16);
}
__device__ __forceinline__ void async_copy16(ushort* lds, const ushort* g) {
  __builtin_amdgcn_global_load_lds((const __attribute__((address_space(1))) void*)g,
                                   (__attribute__((address_space(3))) void*)lds, 16, 0, 0);
}

// ---------------- fused prologue ----------------
// blocks 0..8191: kv/h init (pos inline); 8192..8199: qscale; 8200..10247: weight bf16 conv
__global__ __launch_bounds__(256) void k_pro(const float* __restrict__ x,
                                             const float* __restrict__ value_w,
                                             const float* __restrict__ value_b,
                                             const float* __restrict__ fe,
                                             const float* __restrict__ binary_w,
                                             ushort* __restrict__ kv_bf,
                                             float* __restrict__ h,
                                             const float* __restrict__ film_alpha,
                                             const float* __restrict__ film_a,
                                             float* __restrict__ qscale,
                                             const float* __restrict__ qw,
                                             const float* __restrict__ kw,
                                             const float* __restrict__ vw,
                                             const float* __restrict__ w1,
                                             const float* __restrict__ w2,
                                             const float* __restrict__ cw1,
                                             ushort* __restrict__ o) {
  if (blockIdx.x < 8192) {
    int idx = blockIdx.x * 256 + threadIdx.x;   // over B*D*E = 2M
    int e = idx & (EE - 1);
    int d = (idx >> 8) & (DD - 1);
    int b = idx >> 18;
    float p = fe[d * EE + e];
    int code = d + 1;
    #pragma unroll
    for (int bit = 0; bit < NBITS; bit++) {
      float cb = (float)((code >> (NBITS - 1 - bit)) & 1) - 0.5f;
      p += cb * binary_w[e * NBITS + bit];
    }
    kv_bf[idx] = f2bf(x[b * DD + d] * value_w[e] + value_b[e] + p);
    h[idx] = p;
  } else if (blockIdx.x < 8200) {
    __shared__ float red[256];
    int b = blockIdx.x - 8192, t = threadIdx.x;
    float s = 0.f;
    #pragma unroll
    for (int i = 0; i < 4; i++) s += x[b * DD + t + i * 256];
    red[t] = s; __syncthreads();
    for (int off = 128; off > 0; off >>= 1) {
      if (t < off) red[t] += red[t + off];
      __syncthreads();
    }
    float total = red[0];
    float ta = tanhf(film_alpha[0]);
    float fa = film_a[0];
    #pragma unroll
    for (int i = 0; i < 4; i++) {
      int d = t + i * 256;
      float xn = (total - x[b * DD + d]) / 1023.0f;
      float qs = 1.0f + ta * tanhf(fa * xn);
      qs = fminf(fmaxf(qs, 0.7f), 1.3f);
      qscale[b * DD + d] = qs;
    }
  } else {
    int i = (int)(blockIdx.x - 8200) * 256 + threadIdx.x;
    float v;
    if (i < 65536) v = qw[i];
    else if (i < 131072) v = kw[i - 65536];
    else if (i < 196608) v = vw[i - 131072];
    else if (i < 327680) v = w1[i - 196608];
    else if (i < 458752) v = w2[i - 327680];
    else v = cw1[i - 458752];
    o[i] = f2bf(v);
  }
}

// ---------------- MFMA GEMM for KV projection (unchanged) ----------------
template <int KT>
__global__ __launch_bounds__(512) void kvgemm_k(const ushort* __restrict__ A,
                                                const ushort* __restrict__ Bw,
                                                ushort* __restrict__ C,
                                                ushort* __restrict__ C2) {
  __shared__ ushort As[2][128 * 64];
  __shared__ ushort Bs[2][64 * 64];
  int tid = threadIdx.x;
  int w = tid >> 6, lane = tid & 63;
  int c = lane & 15, g = lane >> 4;
  int wr = w >> 1, wc = w & 1;
  int lr = lane >> 3, lsl = lane & 7;

  const ushort* Ab = A + (size_t)(blockIdx.y * 128) * KT;
  const ushort* Bb = Bw + (size_t)(blockIdx.x * 64) * KT;

  f4 acc[2][2] = {};
  const int NT = KT / 64;

#define STAGE(buf, kt) do {                                                                   \
    _Pragma("unroll")                                                                         \
    for (int j = 0; j < 2; j++) {                                                             \
      int rl = j * 64 + w * 8 + lr;                                                           \
      int slot = lsl ^ (rl & 7);                                                              \
      async_copy16(&As[buf][(j * 64 + w * 8) * 64], Ab + (size_t)rl * KT + (kt) * 64 + slot * 8); \
    }                                                                                         \
    { int rl = w * 8 + lr; int slot = lsl ^ (rl & 7);                                         \
      async_copy16(&Bs[buf][(w * 8) * 64], Bb + (size_t)rl * KT + (kt) * 64 + slot * 8); }    \
  } while (0)

  STAGE(0, 0);
  __syncthreads();

  #pragma unroll
  for (int kt = 0; kt < NT; kt++) {
    int cur = kt & 1;
    if (kt + 1 < NT) STAGE(cur ^ 1, kt + 1);
    #pragma unroll
    for (int ks2 = 0; ks2 < 2; ks2++) {
      short8 af[2], bf_[2];
      #pragma unroll
      for (int mi = 0; mi < 2; mi++) {
        int rowl = wr * 32 + mi * 16 + c;
        int slot = (ks2 * 4 + g) ^ (rowl & 7);
        af[mi] = *(const short8*)&As[cur][rowl * 64 + slot * 8];
      }
      #pragma unroll
      for (int ni = 0; ni < 2; ni++) {
        int rowl = wc * 32 + ni * 16 + c;
        int slot = (ks2 * 4 + g) ^ (rowl & 7);
        bf_[ni] = *(const short8*)&Bs[cur][rowl * 64 + slot * 8];
      }
      #pragma unroll
      for (int mi = 0; mi < 2; mi++)
        #pragma unroll
        for (int ni = 0; ni < 2; ni++)
          acc[mi][ni] = __builtin_amdgcn_mfma_f32_16x16x32_bf16(af[mi], bf_[ni], acc[mi][ni], 0, 0, 0);
    }
    __syncthreads();
  }
#undef STAGE

  int m0 = blockIdx.y * 128 + wr * 32;
  int n0 = blockIdx.x * 64 + wc * 32;
  #pragma unroll
  for (int mi = 0; mi < 2; mi++) {
    #pragma unroll
    for (int ni = 0; ni < 2; ni++) {
      #pragma unroll
      for (int r = 0; r < 4; r++) {
        int row = m0 + mi * 16 + 4 * g + r;
        int col = n0 + ni * 16 + c;
        float v = acc[mi][ni][r];
        int bI = row >> 10, dI = row & 1023;
        if (col < 256) {
          int hI = col >> 5, eI = col & 31;
          C[(((size_t)(bI * HH + hI)) * DD + dI) * HDD + eI] = f2bf(v);
        } else {
          int ch = col - 256;
          int hI = ch >> 5, eI = ch & 31;
          C2[(((size_t)(bI * HH + hI)) * HDD + eI) * DD + dI] = f2bf(v);
        }
      }
    }
  }
}

// ---------------- megakernel v2: 512 blocks x 16 rows, 8 waves (wave = head) ----------------
// LDS 46 KB -> 2 blocks/CU (4 waves/SIMD): doubled TLP vs r16's 1-block/CU.
// Single 16-query group per wave -> ~110 live VGPRs, fits the 128 cap (4 waves/EU) with no spill.
__global__ __launch_bounds__(512, 4) void mega_k(const float* __restrict__ h0,
                                              const ushort* __restrict__ qwb,
                                              const float* __restrict__ qscale,
                                              const ushort* __restrict__ Kbf,
                                              const ushort* __restrict__ Vtb,
                                              const float* __restrict__ gamma_attn,
                                              const float* __restrict__ strength_p,
                                              const float* __restrict__ lnw,
                                              const float* __restrict__ lnb,
                                              const ushort* __restrict__ w1b,
                                              const float* __restrict__ fb1,
                                              const ushort* __restrict__ w2b,
                                              const float* __restrict__ fb2,
                                              const float* __restrict__ gamma_ffn,
                                              const float* __restrict__ clnw,
                                              const float* __restrict__ clnb,
                                              const ushort* __restrict__ cw1b,
                                              const float* __restrict__ cb1,
                                              const float* __restrict__ cw2,
                                              const float* __restrict__ cb2,
                                              float* __restrict__ out) {
  __shared__ __align__(16) float hs[16][256];       // persistent fp32 residual (16 KB)
  __shared__ __align__(16) ushort S1[16 * 256];     // time-shared: hsb / ybs (8 KB)
  __shared__ __align__(16) char Rb[22528];          // time-shared: Pl / upd / t-half / red

  ushort (*Pl)[16][88] = (ushort (*)[16][88])Rb;    // [8][16][88] = 22528 B
  float (*upd)[260]    = (float (*)[260])Rb;        // 16*260*4 = 16640 B
  ushort* tt           = (ushort*)Rb;               // t half: [16][256] bf16 = 8192 B
  float (*red)[16]     = (float (*)[16])Rb;         // tail reduce [8][16]

  int tid = threadIdx.x;
  int w = tid >> 6, lane = tid & 63;
  int c = lane & 15, g = lane >> 4;
  int lid = ((blockIdx.x & 7) << 6) + (blockIdx.x >> 3);   // batch == XCD
  int b = lid >> 6;
  int chunk = lid & 63;
  int q0 = chunk * 16;
  int hh = w;
  int bh = b * HH + hh;
  int dtile = chunk >> 2;
  float ss = fmaxf(strength_p[0], 0.f) * exp2f(-(float)hh / 8.0f);
  const float L2E = 1.4426950408889634f;

  // ---- stage hs (fp32) + hsb (bf16, XOR-swizzled) : 1024 float4 over 512 threads ----
  #pragma unroll
  for (int i = 0; i < 2; i++) {
    int j = tid + i * 512;          // 0..1023
    int row = j >> 6;
    int col = (j & 63) * 4;
    const float4 v = *(const float4*)&h0[((size_t)(b * DD + q0 + row)) * EE + col];
    *(float4*)&hs[row][col] = v;
    ushort4 o;
    o.x = f2bf(v.x); o.y = f2bf(v.y); o.z = f2bf(v.z); o.w = f2bf(v.w);
    int sp = (col >> 3) ^ (row & 7);
    *(ushort4*)&S1[row * 256 + sp * 8 + (col & 7)] = o;
  }
  __syncthreads();

  #pragma unroll 1
  for (int layer = 0; layer < 2; layer++) {
    // ---- fused Q projection: 16 rows, this wave's head, K=256 ----
    short8 qf;
    {
      f4 qa0 = {0.f, 0.f, 0.f, 0.f}, qa1 = {0.f, 0.f, 0.f, 0.f};
      int rowA = c;
      const ushort* Bb0 = qwb + ((size_t)(hh * HDD + c)) * EE + 8 * g;
      const ushort* Bb1 = Bb0 + (size_t)16 * EE;
      #pragma unroll
      for (int kk = 0; kk < 8; kk++) {
        int sp = (kk * 4 + g) ^ (rowA & 7);
        short8 a  = *(const short8*)&S1[rowA * 256 + sp * 8];
        short8 b0 = *(const short8*)(Bb0 + kk * 32);
        short8 b1 = *(const short8*)(Bb1 + kk * 32);
        qa0 = __builtin_amdgcn_mfma_f32_16x16x32_bf16(a, b0, qa0, 0, 0, 0);
        qa1 = __builtin_amdgcn_mfma_f32_16x16x32_bf16(a, b1, qa1, 0, 0, 0);
      }
      const float4 qsv = *(const float4*)&qscale[b * DD + q0 + 4 * g];
      float qs[4] = {qsv.x, qsv.y, qsv.z, qsv.w};
      #pragma unroll
      for (int r = 0; r < 4; r++) {
        float sc = qs[r] * 0.17677669529663687f;
        Pl[w][4 * g + r][c]      = f2bf(qa0[r] * sc);
        Pl[w][4 * g + r][16 + c] = f2bf(qa1[r] * sc);
      }
      qf = *(const short8*)&Pl[w][c][8 * g];   // wave-internal in-order
    }

    // ---- banded attention, static softmax ----
    int Wi = (ss > 1e-8f) ? (int)fminf(14.0f / ss, 1.0e6f) : 1000000;
    int hi = min(15, (q0 + 15 + Wi) >> 6);
    int tlo = q0 - 63 - Wi;
    int lo = (tlo <= 0) ? 0 : ((tlo + 63) >> 6);

    f4 oacc0 = {0.f, 0.f, 0.f, 0.f};
    f4 oacc1 = {0.f, 0.f, 0.f, 0.f};
    float lpart = 0.f;
    int qg = q0 + c;
    const ushort* Kb0 = Kbf + (((size_t)bh * DD + c) << 5) + (g << 3);
    const ushort* Vb0 = Vtb + ((size_t)(bh * HDD + c)) * DD + (g << 3);

    #pragma unroll 1
    for (int ks = lo; ks <= hi; ks++) {
      short8 kf[4];
      #pragma unroll
      for (int t = 0; t < 4; t++)
        kf[t] = *(const short8*)(Kb0 + (((size_t)(ks * 64 + t * 16)) << 5));
      const ushort* vb = Vb0 + ks * 64;
      short8 va0 = *(const short8*)(vb);
      short8 va1 = *(const short8*)(vb + 32);
      short8 vc0 = *(const short8*)(vb + (size_t)16 * DD);
      short8 vc1 = *(const short8*)(vb + (size_t)16 * DD + 32);
      f4 z = {0.f, 0.f, 0.f, 0.f};
      f4 sa[4];
      #pragma unroll
      for (int t = 0; t < 4; t++)
        sa[t] = __builtin_amdgcn_mfma_f32_16x16x32_bf16(kf[t], qf, z, 0, 0, 0);
      float s[16];
      if (ks == dtile) {
        #pragma unroll
        for (int t = 0; t < 4; t++) {
          #pragma unroll
          for (int r = 0; r < 4; r++) {
            int k = ks * 64 + t * 16 + 4 * g + r;
            float ad = fabsf((float)(qg - k));
            s[t * 4 + r] = (k == qg) ? -1e30f : fmaf(-ss, ad, sa[t][r]);
          }
        }
      } else {
        float sgn = (ks > dtile) ? -ss : ss;   // bias = sgn*(k - qg) <= 0
        int kb2 = ks * 64 + 4 * g - qg;
        #pragma unroll
        for (int t = 0; t < 4; t++) {
          #pragma unroll
          for (int r = 0; r < 4; r++) {
            float dk = (float)(kb2 + t * 16 + r);
            s[t * 4 + r] = fmaf(sgn, dk, sa[t][r]);
          }
        }
      }
      #pragma unroll
      for (int i = 0; i < 16; i++) {
        float p = exp2f(s[i] * L2E);
        s[i] = p;
        lpart += p;
      }
      #pragma unroll
      for (int t = 0; t < 4; t++) {
        uint2 u;
        u.x = __builtin_amdgcn_perm(__float_as_uint(s[t * 4 + 1]), __float_as_uint(s[t * 4 + 0]), 0x07060302u);
        u.y = __builtin_amdgcn_perm(__float_as_uint(s[t * 4 + 3]), __float_as_uint(s[t * 4 + 2]), 0x07060302u);
        *(uint2*)&Pl[w][c][t * 16 + 4 * g] = u;
      }
      short8 pa0 = *(const short8*)&Pl[w][c][8 * g];
      short8 pa1 = *(const short8*)&Pl[w][c][32 + 8 * g];
      oacc0 = __builtin_amdgcn_mfma_f32_16x16x32_bf16(pa0, va0, oacc0, 0, 0, 0);
      oacc1 = __builtin_amdgcn_mfma_f32_16x16x32_bf16(pa0, vc0, oacc1, 0, 0, 0);
      oacc0 = __builtin_amdgcn_mfma_f32_16x16x32_bf16(pa1, va1, oacc0, 0, 0, 0);
      oacc1 = __builtin_amdgcn_mfma_f32_16x16x32_bf16(pa1, vc1, oacc1, 0, 0, 0);
    }
    lpart += __shfl_xor(lpart, 16);
    lpart += __shfl_xor(lpart, 32);
    float linv = 1.0f / lpart;
    __syncthreads();   // Pl dead everywhere -> R becomes upd

    // ---- deposit gamma_attn * O / l into upd ----
    #pragma unroll
    for (int r = 0; r < 4; r++) {
      float li = __shfl(linv, 4 * g + r);
      int row = 4 * g + r;
      int e0 = hh * HDD + c, e1 = hh * HDD + 16 + c;
      upd[row][e0] = gamma_attn[e0] * oacc0[r] * li;
      upd[row][e1] = gamma_attn[e1] * oacc1[r] * li;
    }
    __syncthreads();

    // ---- residual + LayerNorm -> ybs (S1); wave w rows 2w, 2w+1 ----
    #pragma unroll
    for (int rr = 0; rr < 2; rr++) {
      int row = 2 * w + rr;
      const float4 hv = *(const float4*)&hs[row][4 * lane];
      const float4 uv = *(const float4*)&upd[row][4 * lane];
      float4 v;
      v.x = hv.x + uv.x; v.y = hv.y + uv.y; v.z = hv.z + uv.z; v.w = hv.w + uv.w;
      *(float4*)&hs[row][4 * lane] = v;
      float s  = v.x + v.y + v.z + v.w;
      float s2 = v.x * v.x + v.y * v.y + v.z * v.z + v.w * v.w;
      #pragma unroll
      for (int off = 32; off; off >>= 1) {
        s  += __shfl_xor(s, off);
        s2 += __shfl_xor(s2, off);
      }
      float mean = s * (1.0f / EE);
      float var = s2 * (1.0f / EE) - mean * mean;
      float rs = rsqrtf(var + 1e-5f);
      const float4 wv = *(const float4*)&lnw[4 * lane];
      const float4 bv = *(const float4*)&lnb[4 * lane];
      ushort4 o;
      o.x = f2bf((v.x - mean) * rs * wv.x + bv.x);
      o.y = f2bf((v.y - mean) * rs * wv.y + bv.y);
      o.z = f2bf((v.z - mean) * rs * wv.z + bv.z);
      o.w = f2bf((v.w - mean) * rs * wv.w + bv.w);
      int sp = (lane >> 1) ^ (row & 7);
      *(ushort4*)&S1[row * 256 + sp * 8 + (lane & 1) * 4] = o;
    }
    __syncthreads();   // ybs + hs(post-attn) complete; upd dead -> R becomes t

    // ---- FFN: two 256-col halves; t half staged in R ----
    f4 acc2[2] = {};
    #pragma unroll 1
    for (int H = 0; H < 2; H++) {
      f4 acc1[2] = {};
      #pragma unroll
      for (int kstep = 0; kstep < 8; kstep++) {
        int row = c;
        int sp = (kstep * 4 + g) ^ (row & 7);
        short8 af = *(const short8*)&S1[row * 256 + sp * 8];
        #pragma unroll
        for (int ni = 0; ni < 2; ni++) {
          int col = H * 256 + w * 32 + ni * 16 + c;
          short8 bf_ = *(const short8*)(w1b + (size_t)col * EE + kstep * 32 + 8 * g);
          acc1[ni] = __builtin_amdgcn_mfma_f32_16x16x32_bf16(af, bf_, acc1[ni], 0, 0, 0);
        }
      }
      // GELU -> t (bf16, swizzled)
      #pragma unroll
      for (int ni = 0; ni < 2; ni++) {
        #pragma unroll
        for (int r = 0; r < 4; r++) {
          int row = 4 * g + r;
          int colH = w * 32 + ni * 16 + c;
          float v = acc1[ni][r] + fb1[H * 256 + colH];
          float gl = 0.5f * v * (1.0f + erff(v * 0.70710678118654752f));
          int sp = (colH >> 3) ^ (row & 7);
          tt[row * 256 + sp * 8 + (colH & 7)] = f2bf(gl);
        }
      }
      __syncthreads();   // t(H) ready
      #pragma unroll
      for (int kstep = 0; kstep < 8; kstep++) {
        int row = c;
        int sp = (kstep * 4 + g) ^ (row & 7);
        short8 af = *(const short8*)&tt[row * 256 + sp * 8];
        #pragma unroll
        for (int ni = 0; ni < 2; ni++) {
          int col = w * 32 + ni * 16 + c;
          short8 bf_ = *(const short8*)(w2b + (size_t)col * 512 + H * 256 + kstep * 32 + 8 * g);
          acc2[ni] = __builtin_amdgcn_mfma_f32_16x16x32_bf16(af, bf_, acc2[ni], 0, 0, 0);
        }
      }
      __syncthreads();   // t reads done (safe to overwrite next half)
    }
    // FFN residual into hs (each lane owns unique (row,col))
    #pragma unroll
    for (int ni = 0; ni < 2; ni++) {
      #pragma unroll
      for (int r = 0; r < 4; r++) {
        int row = 4 * g + r;
        int col = w * 32 + ni * 16 + c;
        float v = acc2[ni][r] + fb2[col];
        hs[row][col] += gamma_ffn[col] * v;
      }
    }
    __syncthreads();   // hs final for this layer

    // ---- refresh hsb for next layer's Q-proj ----
    if (layer == 0) {
      #pragma unroll
      for (int i = 0; i < 2; i++) {
        int j = tid + i * 512;
        int row = j >> 6;
        int col = (j & 63) * 4;
        const float4 v = *(const float4*)&hs[row][col];
        ushort4 o;
        o.x = f2bf(v.x); o.y = f2bf(v.y); o.z = f2bf(v.z); o.w = f2bf(v.w);
        int sp = (col >> 3) ^ (row & 7);
        *(ushort4*)&S1[row * 256 + sp * 8 + (col & 7)] = o;
      }
      __syncthreads();
    }
  }

  // ---- correction head: LN -> GEMM(+b1, GELU) -> dot w2 -> out ----
  #pragma unroll
  for (int rr = 0; rr < 2; rr++) {
    int row = 2 * w + rr;
    const float4 v = *(const float4*)&hs[row][4 * lane];
    float s  = v.x + v.y + v.z + v.w;
    float s2 = v.x * v.x + v.y * v.y + v.z * v.z + v.w * v.w;
    #pragma unroll
    for (int off = 32; off; off >>= 1) {
      s  += __shfl_xor(s, off);
      s2 += __shfl_xor(s2, off);
    }
    float mean = s * (1.0f / EE);
    float var = s2 * (1.0f / EE) - mean * mean;
    float rs = rsqrtf(var + 1e-5f);
    const float4 wv = *(const float4*)&clnw[4 * lane];
    const float4 bv = *(const float4*)&clnb[4 * lane];
    ushort4 o;
    o.x = f2bf((v.x - mean) * rs * wv.x + bv.x);
    o.y = f2bf((v.y - mean) * rs * wv.y + bv.y);
    o.z = f2bf((v.z - mean) * rs * wv.z + bv.z);
    o.w = f2bf((v.w - mean) * rs * wv.w + bv.w);
    int sp = (lane >> 1) ^ (row & 7);
    *(ushort4*)&S1[row * 256 + sp * 8 + (lane & 1) * 4] = o;
  }
  __syncthreads();

  f4 acc[2] = {};
  #pragma unroll
  for (int kstep = 0; kstep < 8; kstep++) {
    int row = c;
    int sp = (kstep * 4 + g) ^ (row & 7);
    short8 af = *(const short8*)&S1[row * 256 + sp * 8];
    #pragma unroll
    for (int ni = 0; ni < 2; ni++) {
      int col = w * 32 + ni * 16 + c;
      short8 bf_ = *(const short8*)(cw1b + (size_t)col * EE + kstep * 32 + 8 * g);
      acc[ni] = __builtin_amdgcn_mfma_f32_16x16x32_bf16(af, bf_, acc[ni], 0, 0, 0);
    }
  }
  float b1v[2], w2v[2];
  #pragma unroll
  for (int ni = 0; ni < 2; ni++) {
    int col = w * 32 + ni * 16 + c;
    b1v[ni] = cb1[col];
    w2v[ni] = cw2[col];
  }
  __syncthreads();   // S1 reads done block-wide before red overlays R
  #pragma unroll
  for (int r = 0; r < 4; r++) {
    float s = 0.f;
    #pragma unroll
    for (int ni = 0; ni < 2; ni++) {
      float v = acc[ni][r] + b1v[ni];
      float gl = 0.5f * v * (1.0f + erff(v * 0.70710678118654752f));
      s += gl * w2v[ni];
    }
    s += __shfl_xor(s, 1);
    s += __shfl_xor(s, 2);
    s += __shfl_xor(s, 4);
    s += __shfl_xor(s, 8);
    if (c == 0) red[w][4 * g + r] = s;
  }
  __syncthreads();
  if (tid < 16) {
    float s = 0.f;
    #pragma unroll
    for (int ww = 0; ww < 8; ww++) s += red[ww][tid];
    out[(b << 10) + q0 + tid] = s + cb2[0];
  }
}

extern "C" void kernel_launch(void* const* d_in, const int* in_sizes, int n_in,
                              void* d_out, int out_size, void* d_ws, size_t ws_size,
                              hipStream_t stream) {
  const float* x            = (const float*)d_in[0];
  const float* value_w      = (const float*)d_in[1];
  const float* value_b      = (const float*)d_in[2];
  const float* feature_embed= (const float*)d_in[3];
  const float* binary_w     = (const float*)d_in[4];
  const float* qw           = (const float*)d_in[5];
  const float* kw           = (const float*)d_in[6];
  const float* vw           = (const float*)d_in[7];
  const float* film_alpha   = (const float*)d_in[8];
  const float* film_a       = (const float*)d_in[9];
  const float* ln1_w        = (const float*)d_in[10];
  const float* ln1_b        = (const float*)d_in[11];
  const float* ffn_w1       = (const float*)d_in[12];
  const float* ffn_b1       = (const float*)d_in[13];
  const float* ffn_w2       = (const float*)d_in[14];
  const float* ffn_b2       = (const float*)d_in[15];
  const float* gamma_attn   = (const float*)d_in[16];
  const float* gamma_ffn    = (const float*)d_in[17];
  const float* corr_ln_w    = (const float*)d_in[18];
  const float* corr_ln_b    = (const float*)d_in[19];
  const float* corr_w1      = (const float*)d_in[20];
  const float* corr_b1      = (const float*)d_in[21];
  const float* corr_w2      = (const float*)d_in[22];
  const float* corr_b2      = (const float*)d_in[23];
  const float* alibi_strength=(const float*)d_in[24];

  const size_t ME = (size_t)BD * DD * EE;   // 2M
  float* ws = (float*)d_ws;
  float* qscale = ws;                       // 8192 f
  float* hb     = qscale + BD * DD;         // 2M f
  ushort* kv_bf = (ushort*)(hb + ME);       // 2M us
  ushort* Kbf   = kv_bf + ME;               // 2M us
  ushort* Vtb   = Kbf + ME;                 // 2M us
  ushort* wbf   = Vtb + ME;                 // 524288 us
  ushort* qwb   = wbf;
  ushort* kwb   = wbf + 65536;              // kw rows 0-255, vw rows 256-511 (contiguous)
  ushort* w1b   = wbf + 196608;
  ushort* w2b   = wbf + 327680;
  ushort* cw1b  = wbf + 458752;

  const int M = BD * DD;   // 8192

  k_pro<<<8192 + 8 + 2048, 256, 0, stream>>>(x, value_w, value_b, feature_embed, binary_w,
                                             kv_bf, hb,
                                             film_alpha, film_a, qscale,
                                             qw, kw, vw, ffn_w1, ffn_w2, corr_w1, wbf);

  kvgemm_k<256><<<dim3(512 / 64, M / 128), 512, 0, stream>>>(kv_bf, kwb, Kbf, Vtb);

  mega_k<<<dim3(512), 512, 0, stream>>>(hb, qwb, qscale, Kbf, Vtb,
                                        gamma_attn, alibi_strength,
                                        ln1_w, ln1_b,
                                        w1b, ffn_b1, w2b, ffn_b2, gamma_ffn,
                                        corr_ln_w, corr_ln_b,
                                        cw1b, corr_b1, corr_w2, corr_b2,
                                        (float*)d_out);
}

// Round 18
// 403.421 us; speedup vs baseline: 1.0035x; 1.0035x over previous
//
#include <hip/hip_runtime.h>
#include <math.h>

#define BD 8
#define DD 1024
#define EE 256
#define HH 8
#define HDD 32
#define NBITS 11

typedef __attribute__((ext_vector_type(8))) short short8;
typedef __attribute__((ext_vector_type(4))) float f4;

__device__ __forceinline__ ushort f2bf(float f) {
  unsigned u = __float_as_uint(f);
  u += 0x7fffu + ((u >> 16) & 1u);
  return (ushort)(u >> 16);
}
__device__ __forceinline__ void async_copy16(ushort* lds, const ushort* g) {
  __builtin_amdgcn_global_load_lds((const __attribute__((address_space(1))) void*)g,
                                   (__attribute__((address_space(3))) void*)lds, 16, 0, 0);
}

// ---------------- fused prologue ----------------
// blocks 0..8191: kv/h init (pos inline); 8192..8199: qscale; 8200..10247: weight bf16 conv
__global__ __launch_bounds__(256) void k_pro(const float* __restrict__ x,
                                             const float* __restrict__ value_w,
                                             const float* __restrict__ value_b,
                                             const float* __restrict__ fe,
                                             const float* __restrict__ binary_w,
                                             ushort* __restrict__ kv_bf,
                                             float* __restrict__ h,
                                             const float* __restrict__ film_alpha,
                                             const float* __restrict__ film_a,
                                             float* __restrict__ qscale,
                                             const float* __restrict__ qw,
                                             const float* __restrict__ kw,
                                             const float* __restrict__ vw,
                                             const float* __restrict__ w1,
                                             const float* __restrict__ w2,
                                             const float* __restrict__ cw1,
                                             ushort* __restrict__ o) {
  if (blockIdx.x < 8192) {
    int idx = blockIdx.x * 256 + threadIdx.x;   // over B*D*E = 2M
    int e = idx & (EE - 1);
    int d = (idx >> 8) & (DD - 1);
    int b = idx >> 18;
    float p = fe[d * EE + e];
    int code = d + 1;
    #pragma unroll
    for (int bit = 0; bit < NBITS; bit++) {
      float cb = (float)((code >> (NBITS - 1 - bit)) & 1) - 0.5f;
      p += cb * binary_w[e * NBITS + bit];
    }
    kv_bf[idx] = f2bf(x[b * DD + d] * value_w[e] + value_b[e] + p);
    h[idx] = p;
  } else if (blockIdx.x < 8200) {
    __shared__ float red[256];
    int b = blockIdx.x - 8192, t = threadIdx.x;
    float s = 0.f;
    #pragma unroll
    for (int i = 0; i < 4; i++) s += x[b * DD + t + i * 256];
    red[t] = s; __syncthreads();
    for (int off = 128; off > 0; off >>= 1) {
      if (t < off) red[t] += red[t + off];
      __syncthreads();
    }
    float total = red[0];
    float ta = tanhf(film_alpha[0]);
    float fa = film_a[0];
    #pragma unroll
    for (int i = 0; i < 4; i++) {
      int d = t + i * 256;
      float xn = (total - x[b * DD + d]) / 1023.0f;
      float qs = 1.0f + ta * tanhf(fa * xn);
      qs = fminf(fmaxf(qs, 0.7f), 1.3f);
      qscale[b * DD + d] = qs;
    }
  } else {
    int i = (int)(blockIdx.x - 8200) * 256 + threadIdx.x;
    float v;
    if (i < 65536) v = qw[i];
    else if (i < 131072) v = kw[i - 65536];
    else if (i < 196608) v = vw[i - 131072];
    else if (i < 327680) v = w1[i - 196608];
    else if (i < 458752) v = w2[i - 327680];
    else v = cw1[i - 458752];
    o[i] = f2bf(v);
  }
}

// ---------------- MFMA GEMM for KV projection (unchanged) ----------------
template <int KT>
__global__ __launch_bounds__(512) void kvgemm_k(const ushort* __restrict__ A,
                                                const ushort* __restrict__ Bw,
                                                ushort* __restrict__ C,
                                                ushort* __restrict__ C2) {
  __shared__ ushort As[2][128 * 64];
  __shared__ ushort Bs[2][64 * 64];
  int tid = threadIdx.x;
  int w = tid >> 6, lane = tid & 63;
  int c = lane & 15, g = lane >> 4;
  int wr = w >> 1, wc = w & 1;
  int lr = lane >> 3, lsl = lane & 7;

  const ushort* Ab = A + (size_t)(blockIdx.y * 128) * KT;
  const ushort* Bb = Bw + (size_t)(blockIdx.x * 64) * KT;

  f4 acc[2][2] = {};
  const int NT = KT / 64;

#define STAGE(buf, kt) do {                                                                   \
    _Pragma("unroll")                                                                         \
    for (int j = 0; j < 2; j++) {                                                             \
      int rl = j * 64 + w * 8 + lr;                                                           \
      int slot = lsl ^ (rl & 7);                                                              \
      async_copy16(&As[buf][(j * 64 + w * 8) * 64], Ab + (size_t)rl * KT + (kt) * 64 + slot * 8); \
    }                                                                                         \
    { int rl = w * 8 + lr; int slot = lsl ^ (rl & 7);                                         \
      async_copy16(&Bs[buf][(w * 8) * 64], Bb + (size_t)rl * KT + (kt) * 64 + slot * 8); }    \
  } while (0)

  STAGE(0, 0);
  __syncthreads();

  #pragma unroll
  for (int kt = 0; kt < NT; kt++) {
    int cur = kt & 1;
    if (kt + 1 < NT) STAGE(cur ^ 1, kt + 1);
    #pragma unroll
    for (int ks2 = 0; ks2 < 2; ks2++) {
      short8 af[2], bf_[2];
      #pragma unroll
      for (int mi = 0; mi < 2; mi++) {
        int rowl = wr * 32 + mi * 16 + c;
        int slot = (ks2 * 4 + g) ^ (rowl & 7);
        af[mi] = *(const short8*)&As[cur][rowl * 64 + slot * 8];
      }
      #pragma unroll
      for (int ni = 0; ni < 2; ni++) {
        int rowl = wc * 32 + ni * 16 + c;
        int slot = (ks2 * 4 + g) ^ (rowl & 7);
        bf_[ni] = *(const short8*)&Bs[cur][rowl * 64 + slot * 8];
      }
      #pragma unroll
      for (int mi = 0; mi < 2; mi++)
        #pragma unroll
        for (int ni = 0; ni < 2; ni++)
          acc[mi][ni] = __builtin_amdgcn_mfma_f32_16x16x32_bf16(af[mi], bf_[ni], acc[mi][ni], 0, 0, 0);
    }
    __syncthreads();
  }
#undef STAGE

  int m0 = blockIdx.y * 128 + wr * 32;
  int n0 = blockIdx.x * 64 + wc * 32;
  #pragma unroll
  for (int mi = 0; mi < 2; mi++) {
    #pragma unroll
    for (int ni = 0; ni < 2; ni++) {
      #pragma unroll
      for (int r = 0; r < 4; r++) {
        int row = m0 + mi * 16 + 4 * g + r;
        int col = n0 + ni * 16 + c;
        float v = acc[mi][ni][r];
        int bI = row >> 10, dI = row & 1023;
        if (col < 256) {
          int hI = col >> 5, eI = col & 31;
          C[(((size_t)(bI * HH + hI)) * DD + dI) * HDD + eI] = f2bf(v);
        } else {
          int ch = col - 256;
          int hI = ch >> 5, eI = ch & 31;
          C2[(((size_t)(bI * HH + hI)) * HDD + eI) * DD + dI] = f2bf(v);
        }
      }
    }
  }
}

// ---------------- megakernel v2: 512 blocks x 16 rows, 8 waves (wave = head) ----------------
// LDS 46 KB -> 2 blocks/CU (4 waves/SIMD): doubled TLP vs r16's 1-block/CU.
// Single 16-query group per wave -> ~110 live VGPRs, fits the 128 cap (4 waves/EU) with no spill.
__global__ __launch_bounds__(512, 4) void mega_k(const float* __restrict__ h0,
                                              const ushort* __restrict__ qwb,
                                              const float* __restrict__ qscale,
                                              const ushort* __restrict__ Kbf,
                                              const ushort* __restrict__ Vtb,
                                              const float* __restrict__ gamma_attn,
                                              const float* __restrict__ strength_p,
                                              const float* __restrict__ lnw,
                                              const float* __restrict__ lnb,
                                              const ushort* __restrict__ w1b,
                                              const float* __restrict__ fb1,
                                              const ushort* __restrict__ w2b,
                                              const float* __restrict__ fb2,
                                              const float* __restrict__ gamma_ffn,
                                              const float* __restrict__ clnw,
                                              const float* __restrict__ clnb,
                                              const ushort* __restrict__ cw1b,
                                              const float* __restrict__ cb1,
                                              const float* __restrict__ cw2,
                                              const float* __restrict__ cb2,
                                              float* __restrict__ out) {
  __shared__ __align__(16) float hs[16][256];       // persistent fp32 residual (16 KB)
  __shared__ __align__(16) ushort S1[16 * 256];     // time-shared: hsb / ybs (8 KB)
  __shared__ __align__(16) char Rb[22528];          // time-shared: Pl / upd / t-half / red

  ushort (*Pl)[16][88] = (ushort (*)[16][88])Rb;    // [8][16][88] = 22528 B
  float (*upd)[260]    = (float (*)[260])Rb;        // 16*260*4 = 16640 B
  ushort* tt           = (ushort*)Rb;               // t half: [16][256] bf16 = 8192 B
  float (*red)[16]     = (float (*)[16])Rb;         // tail reduce [8][16]

  int tid = threadIdx.x;
  int w = tid >> 6, lane = tid & 63;
  int c = lane & 15, g = lane >> 4;
  int lid = ((blockIdx.x & 7) << 6) + (blockIdx.x >> 3);   // batch == XCD
  int b = lid >> 6;
  int chunk = lid & 63;
  int q0 = chunk * 16;
  int hh = w;
  int bh = b * HH + hh;
  int dtile = chunk >> 2;
  float ss = fmaxf(strength_p[0], 0.f) * exp2f(-(float)hh / 8.0f);
  const float L2E = 1.4426950408889634f;

  // ---- stage hs (fp32) + hsb (bf16, XOR-swizzled) : 1024 float4 over 512 threads ----
  #pragma unroll
  for (int i = 0; i < 2; i++) {
    int j = tid + i * 512;          // 0..1023
    int row = j >> 6;
    int col = (j & 63) * 4;
    const float4 v = *(const float4*)&h0[((size_t)(b * DD + q0 + row)) * EE + col];
    *(float4*)&hs[row][col] = v;
    ushort4 o;
    o.x = f2bf(v.x); o.y = f2bf(v.y); o.z = f2bf(v.z); o.w = f2bf(v.w);
    int sp = (col >> 3) ^ (row & 7);
    *(ushort4*)&S1[row * 256 + sp * 8 + (col & 7)] = o;
  }
  __syncthreads();

  #pragma unroll 1
  for (int layer = 0; layer < 2; layer++) {
    // ---- fused Q projection: 16 rows, this wave's head, K=256 ----
    short8 qf;
    {
      f4 qa0 = {0.f, 0.f, 0.f, 0.f}, qa1 = {0.f, 0.f, 0.f, 0.f};
      int rowA = c;
      const ushort* Bb0 = qwb + ((size_t)(hh * HDD + c)) * EE + 8 * g;
      const ushort* Bb1 = Bb0 + (size_t)16 * EE;
      #pragma unroll
      for (int kk = 0; kk < 8; kk++) {
        int sp = (kk * 4 + g) ^ (rowA & 7);
        short8 a  = *(const short8*)&S1[rowA * 256 + sp * 8];
        short8 b0 = *(const short8*)(Bb0 + kk * 32);
        short8 b1 = *(const short8*)(Bb1 + kk * 32);
        qa0 = __builtin_amdgcn_mfma_f32_16x16x32_bf16(a, b0, qa0, 0, 0, 0);
        qa1 = __builtin_amdgcn_mfma_f32_16x16x32_bf16(a, b1, qa1, 0, 0, 0);
      }
      const float4 qsv = *(const float4*)&qscale[b * DD + q0 + 4 * g];
      float qs[4] = {qsv.x, qsv.y, qsv.z, qsv.w};
      #pragma unroll
      for (int r = 0; r < 4; r++) {
        float sc = qs[r] * 0.17677669529663687f;
        Pl[w][4 * g + r][c]      = f2bf(qa0[r] * sc);
        Pl[w][4 * g + r][16 + c] = f2bf(qa1[r] * sc);
      }
      qf = *(const short8*)&Pl[w][c][8 * g];   // wave-internal in-order
    }

    // ---- banded attention, static softmax ----
    int Wi = (ss > 1e-8f) ? (int)fminf(14.0f / ss, 1.0e6f) : 1000000;
    int hi = min(15, (q0 + 15 + Wi) >> 6);
    int tlo = q0 - 63 - Wi;
    int lo = (tlo <= 0) ? 0 : ((tlo + 63) >> 6);

    f4 oacc0 = {0.f, 0.f, 0.f, 0.f};
    f4 oacc1 = {0.f, 0.f, 0.f, 0.f};
    float lpart = 0.f;
    int qg = q0 + c;
    const ushort* Kb0 = Kbf + (((size_t)bh * DD + c) << 5) + (g << 3);
    const ushort* Vb0 = Vtb + ((size_t)(bh * HDD + c)) * DD + (g << 3);

    #pragma unroll 1
    for (int ks = lo; ks <= hi; ks++) {
      short8 kf[4];
      #pragma unroll
      for (int t = 0; t < 4; t++)
        kf[t] = *(const short8*)(Kb0 + (((size_t)(ks * 64 + t * 16)) << 5));
      const ushort* vb = Vb0 + ks * 64;
      short8 va0 = *(const short8*)(vb);
      short8 va1 = *(const short8*)(vb + 32);
      short8 vc0 = *(const short8*)(vb + (size_t)16 * DD);
      short8 vc1 = *(const short8*)(vb + (size_t)16 * DD + 32);
      f4 z = {0.f, 0.f, 0.f, 0.f};
      f4 sa[4];
      #pragma unroll
      for (int t = 0; t < 4; t++)
        sa[t] = __builtin_amdgcn_mfma_f32_16x16x32_bf16(kf[t], qf, z, 0, 0, 0);
      float s[16];
      if (ks == dtile) {
        #pragma unroll
        for (int t = 0; t < 4; t++) {
          #pragma unroll
          for (int r = 0; r < 4; r++) {
            int k = ks * 64 + t * 16 + 4 * g + r;
            float ad = fabsf((float)(qg - k));
            s[t * 4 + r] = (k == qg) ? -1e30f : fmaf(-ss, ad, sa[t][r]);
          }
        }
      } else {
        float sgn = (ks > dtile) ? -ss : ss;   // bias = sgn*(k - qg) <= 0
        int kb2 = ks * 64 + 4 * g - qg;
        #pragma unroll
        for (int t = 0; t < 4; t++) {
          #pragma unroll
          for (int r = 0; r < 4; r++) {
            float dk = (float)(kb2 + t * 16 + r);
            s[t * 4 + r] = fmaf(sgn, dk, sa[t][r]);
          }
        }
      }
      #pragma unroll
      for (int i = 0; i < 16; i++) {
        float p = exp2f(s[i] * L2E);
        s[i] = p;
        lpart += p;
      }
      #pragma unroll
      for (int t = 0; t < 4; t++) {
        uint2 u;
        u.x = __builtin_amdgcn_perm(__float_as_uint(s[t * 4 + 1]), __float_as_uint(s[t * 4 + 0]), 0x07060302u);
        u.y = __builtin_amdgcn_perm(__float_as_uint(s[t * 4 + 3]), __float_as_uint(s[t * 4 + 2]), 0x07060302u);
        *(uint2*)&Pl[w][c][t * 16 + 4 * g] = u;
      }
      short8 pa0 = *(const short8*)&Pl[w][c][8 * g];
      short8 pa1 = *(const short8*)&Pl[w][c][32 + 8 * g];
      oacc0 = __builtin_amdgcn_mfma_f32_16x16x32_bf16(pa0, va0, oacc0, 0, 0, 0);
      oacc1 = __builtin_amdgcn_mfma_f32_16x16x32_bf16(pa0, vc0, oacc1, 0, 0, 0);
      oacc0 = __builtin_amdgcn_mfma_f32_16x16x32_bf16(pa1, va1, oacc0, 0, 0, 0);
      oacc1 = __builtin_amdgcn_mfma_f32_16x16x32_bf16(pa1, vc1, oacc1, 0, 0, 0);
    }
    lpart += __shfl_xor(lpart, 16);
    lpart += __shfl_xor(lpart, 32);
    float linv = 1.0f / lpart;
    __syncthreads();   // Pl dead everywhere -> R becomes upd

    // ---- deposit gamma_attn * O / l into upd ----
    #pragma unroll
    for (int r = 0; r < 4; r++) {
      float li = __shfl(linv, 4 * g + r);
      int row = 4 * g + r;
      int e0 = hh * HDD + c, e1 = hh * HDD + 16 + c;
      upd[row][e0] = gamma_attn[e0] * oacc0[r] * li;
      upd[row][e1] = gamma_attn[e1] * oacc1[r] * li;
    }
    __syncthreads();

    // ---- residual + LayerNorm -> ybs (S1); wave w rows 2w, 2w+1 ----
    #pragma unroll
    for (int rr = 0; rr < 2; rr++) {
      int row = 2 * w + rr;
      const float4 hv = *(const float4*)&hs[row][4 * lane];
      const float4 uv = *(const float4*)&upd[row][4 * lane];
      float4 v;
      v.x = hv.x + uv.x; v.y = hv.y + uv.y; v.z = hv.z + uv.z; v.w = hv.w + uv.w;
      *(float4*)&hs[row][4 * lane] = v;
      float s  = v.x + v.y + v.z + v.w;
      float s2 = v.x * v.x + v.y * v.y + v.z * v.z + v.w * v.w;
      #pragma unroll
      for (int off = 32; off; off >>= 1) {
        s  += __shfl_xor(s, off);
        s2 += __shfl_xor(s2, off);
      }
      float mean = s * (1.0f / EE);
      float var = s2 * (1.0f / EE) - mean * mean;
      float rs = rsqrtf(var + 1e-5f);
      const float4 wv = *(const float4*)&lnw[4 * lane];
      const float4 bv = *(const float4*)&lnb[4 * lane];
      ushort4 o;
      o.x = f2bf((v.x - mean) * rs * wv.x + bv.x);
      o.y = f2bf((v.y - mean) * rs * wv.y + bv.y);
      o.z = f2bf((v.z - mean) * rs * wv.z + bv.z);
      o.w = f2bf((v.w - mean) * rs * wv.w + bv.w);
      int sp = (lane >> 1) ^ (row & 7);
      *(ushort4*)&S1[row * 256 + sp * 8 + (lane & 1) * 4] = o;
    }
    __syncthreads();   // ybs + hs(post-attn) complete; upd dead -> R becomes t

    // ---- FFN: two 256-col halves; t half staged in R ----
    f4 acc2[2] = {};
    #pragma unroll 1
    for (int H = 0; H < 2; H++) {
      f4 acc1[2] = {};
      #pragma unroll
      for (int kstep = 0; kstep < 8; kstep++) {
        int row = c;
        int sp = (kstep * 4 + g) ^ (row & 7);
        short8 af = *(const short8*)&S1[row * 256 + sp * 8];
        #pragma unroll
        for (int ni = 0; ni < 2; ni++) {
          int col = H * 256 + w * 32 + ni * 16 + c;
          short8 bf_ = *(const short8*)(w1b + (size_t)col * EE + kstep * 32 + 8 * g);
          acc1[ni] = __builtin_amdgcn_mfma_f32_16x16x32_bf16(af, bf_, acc1[ni], 0, 0, 0);
        }
      }
      // GELU -> t (bf16, swizzled)
      #pragma unroll
      for (int ni = 0; ni < 2; ni++) {
        #pragma unroll
        for (int r = 0; r < 4; r++) {
          int row = 4 * g + r;
          int colH = w * 32 + ni * 16 + c;
          float v = acc1[ni][r] + fb1[H * 256 + colH];
          float gl = 0.5f * v * (1.0f + erff(v * 0.70710678118654752f));
          int sp = (colH >> 3) ^ (row & 7);
          tt[row * 256 + sp * 8 + (colH & 7)] = f2bf(gl);
        }
      }
      __syncthreads();   // t(H) ready
      #pragma unroll
      for (int kstep = 0; kstep < 8; kstep++) {
        int row = c;
        int sp = (kstep * 4 + g) ^ (row & 7);
        short8 af = *(const short8*)&tt[row * 256 + sp * 8];
        #pragma unroll
        for (int ni = 0; ni < 2; ni++) {
          int col = w * 32 + ni * 16 + c;
          short8 bf_ = *(const short8*)(w2b + (size_t)col * 512 + H * 256 + kstep * 32 + 8 * g);
          acc2[ni] = __builtin_amdgcn_mfma_f32_16x16x32_bf16(af, bf_, acc2[ni], 0, 0, 0);
        }
      }
      __syncthreads();   // t reads done (safe to overwrite next half)
    }
    // FFN residual into hs (each lane owns unique (row,col))
    #pragma unroll
    for (int ni = 0; ni < 2; ni++) {
      #pragma unroll
      for (int r = 0; r < 4; r++) {
        int row = 4 * g + r;
        int col = w * 32 + ni * 16 + c;
        float v = acc2[ni][r] + fb2[col];
        hs[row][col] += gamma_ffn[col] * v;
      }
    }
    __syncthreads();   // hs final for this layer

    // ---- refresh hsb for next layer's Q-proj ----
    if (layer == 0) {
      #pragma unroll
      for (int i = 0; i < 2; i++) {
        int j = tid + i * 512;
        int row = j >> 6;
        int col = (j & 63) * 4;
        const float4 v = *(const float4*)&hs[row][col];
        ushort4 o;
        o.x = f2bf(v.x); o.y = f2bf(v.y); o.z = f2bf(v.z); o.w = f2bf(v.w);
        int sp = (col >> 3) ^ (row & 7);
        *(ushort4*)&S1[row * 256 + sp * 8 + (col & 7)] = o;
      }
      __syncthreads();
    }
  }

  // ---- correction head: LN -> GEMM(+b1, GELU) -> dot w2 -> out ----
  #pragma unroll
  for (int rr = 0; rr < 2; rr++) {
    int row = 2 * w + rr;
    const float4 v = *(const float4*)&hs[row][4 * lane];
    float s  = v.x + v.y + v.z + v.w;
    float s2 = v.x * v.x + v.y * v.y + v.z * v.z + v.w * v.w;
    #pragma unroll
    for (int off = 32; off; off >>= 1) {
      s  += __shfl_xor(s, off);
      s2 += __shfl_xor(s2, off);
    }
    float mean = s * (1.0f / EE);
    float var = s2 * (1.0f / EE) - mean * mean;
    float rs = rsqrtf(var + 1e-5f);
    const float4 wv = *(const float4*)&clnw[4 * lane];
    const float4 bv = *(const float4*)&clnb[4 * lane];
    ushort4 o;
    o.x = f2bf((v.x - mean) * rs * wv.x + bv.x);
    o.y = f2bf((v.y - mean) * rs * wv.y + bv.y);
    o.z = f2bf((v.z - mean) * rs * wv.z + bv.z);
    o.w = f2bf((v.w - mean) * rs * wv.w + bv.w);
    int sp = (lane >> 1) ^ (row & 7);
    *(ushort4*)&S1[row * 256 + sp * 8 + (lane & 1) * 4] = o;
  }
  __syncthreads();

  f4 acc[2] = {};
  #pragma unroll
  for (int kstep = 0; kstep < 8; kstep++) {
    int row = c;
    int sp = (kstep * 4 + g) ^ (row & 7);
    short8 af = *(const short8*)&S1[row * 256 + sp * 8];
    #pragma unroll
    for (int ni = 0; ni < 2; ni++) {
      int col = w * 32 + ni * 16 + c;
      short8 bf_ = *(const short8*)(cw1b + (size_t)col * EE + kstep * 32 + 8 * g);
      acc[ni] = __builtin_amdgcn_mfma_f32_16x16x32_bf16(af, bf_, acc[ni], 0, 0, 0);
    }
  }
  float b1v[2], w2v[2];
  #pragma unroll
  for (int ni = 0; ni < 2; ni++) {
    int col = w * 32 + ni * 16 + c;
    b1v[ni] = cb1[col];
    w2v[ni] = cw2[col];
  }
  __syncthreads();   // S1 reads done block-wide before red overlays R
  #pragma unroll
  for (int r = 0; r < 4; r++) {
    float s = 0.f;
    #pragma unroll
    for (int ni = 0; ni < 2; ni++) {
      float v = acc[ni][r] + b1v[ni];
      float gl = 0.5f * v * (1.0f + erff(v * 0.70710678118654752f));
      s += gl * w2v[ni];
    }
    s += __shfl_xor(s, 1);
    s += __shfl_xor(s, 2);
    s += __shfl_xor(s, 4);
    s += __shfl_xor(s, 8);
    if (c == 0) red[w][4 * g + r] = s;
  }
  __syncthreads();
  if (tid < 16) {
    float s = 0.f;
    #pragma unroll
    for (int ww = 0; ww < 8; ww++) s += red[ww][tid];
    out[(b << 10) + q0 + tid] = s + cb2[0];
  }
}

extern "C" void kernel_launch(void* const* d_in, const int* in_sizes, int n_in,
                              void* d_out, int out_size, void* d_ws, size_t ws_size,
                              hipStream_t stream) {
  const float* x            = (const float*)d_in[0];
  const float* value_w      = (const float*)d_in[1];
  const float* value_b      = (const float*)d_in[2];
  const float* feature_embed= (const float*)d_in[3];
  const float* binary_w     = (const float*)d_in[4];
  const float* qw           = (const float*)d_in[5];
  const float* kw           = (const float*)d_in[6];
  const float* vw           = (const float*)d_in[7];
  const float* film_alpha   = (const float*)d_in[8];
  const float* film_a       = (const float*)d_in[9];
  const float* ln1_w        = (const float*)d_in[10];
  const float* ln1_b        = (const float*)d_in[11];
  const float* ffn_w1       = (const float*)d_in[12];
  const float* ffn_b1       = (const float*)d_in[13];
  const float* ffn_w2       = (const float*)d_in[14];
  const float* ffn_b2       = (const float*)d_in[15];
  const float* gamma_attn   = (const float*)d_in[16];
  const float* gamma_ffn    = (const float*)d_in[17];
  const float* corr_ln_w    = (const float*)d_in[18];
  const float* corr_ln_b    = (const float*)d_in[19];
  const float* corr_w1      = (const float*)d_in[20];
  const float* corr_b1      = (const float*)d_in[21];
  const float* corr_w2      = (const float*)d_in[22];
  const float* corr_b2      = (const float*)d_in[23];
  const float* alibi_strength=(const float*)d_in[24];

  const size_t ME = (size_t)BD * DD * EE;   // 2M
  float* ws = (float*)d_ws;
  float* qscale = ws;                       // 8192 f
  float* hb     = qscale + BD * DD;         // 2M f
  ushort* kv_bf = (ushort*)(hb + ME);       // 2M us
  ushort* Kbf   = kv_bf + ME;               // 2M us
  ushort* Vtb   = Kbf + ME;                 // 2M us
  ushort* wbf   = Vtb + ME;                 // 524288 us
  ushort* qwb   = wbf;
  ushort* kwb   = wbf + 65536;              // kw rows 0-255, vw rows 256-511 (contiguous)
  ushort* w1b   = wbf + 196608;
  ushort* w2b   = wbf + 327680;
  ushort* cw1b  = wbf + 458752;

  const int M = BD * DD;   // 8192

  k_pro<<<8192 + 8 + 2048, 256, 0, stream>>>(x, value_w, value_b, feature_embed, binary_w,
                                             kv_bf, hb,
                                             film_alpha, film_a, qscale,
                                             qw, kw, vw, ffn_w1, ffn_w2, corr_w1, wbf);

  kvgemm_k<256><<<dim3(512 / 64, M / 128), 512, 0, stream>>>(kv_bf, kwb, Kbf, Vtb);

  mega_k<<<dim3(512), 512, 0, stream>>>(hb, qwb, qscale, Kbf, Vtb,
                                        gamma_attn, alibi_strength,
                                        ln1_w, ln1_b,
                                        w1b, ffn_b1, w2b, ffn_b2, gamma_ffn,
                                        corr_ln_w, corr_ln_b,
                                        cw1b, corr_b1, corr_w2, corr_b2,
                                        (float*)d_out);
}

// Round 19
// 175.005 us; speedup vs baseline: 2.3133x; 2.3052x over previous
//
#include <hip/hip_runtime.h>
#include <math.h>

#define BD 8
#define DD 1024
#define EE 256
#define HH 8
#define HDD 32
#define NBITS 11

typedef __attribute__((ext_vector_type(8))) short short8;
typedef __attribute__((ext_vector_type(4))) float f4;

__device__ __forceinline__ ushort f2bf(float f) {
  unsigned u = __float_as_uint(f);
  u += 0x7fffu + ((u >> 16) & 1u);
  return (ushort)(u >> 16);
}
__device__ __forceinline__ void async_copy16(ushort* lds, const ushort* g) {
  __builtin_amdgcn_global_load_lds((const __attribute__((address_space(1))) void*)g,
                                   (__attribute__((address_space(3))) void*)lds, 16, 0, 0);
}

// ---------------- fused prologue ----------------
// blocks 0..8191: kv/h init (pos inline); 8192..8199: qscale; 8200..10247: weight bf16 conv
__global__ __launch_bounds__(256) void k_pro(const float* __restrict__ x,
                                             const float* __restrict__ value_w,
                                             const float* __restrict__ value_b,
                                             const float* __restrict__ fe,
                                             const float* __restrict__ binary_w,
                                             ushort* __restrict__ kv_bf,
                                             float* __restrict__ h,
                                             const float* __restrict__ film_alpha,
                                             const float* __restrict__ film_a,
                                             float* __restrict__ qscale,
                                             const float* __restrict__ qw,
                                             const float* __restrict__ kw,
                                             const float* __restrict__ vw,
                                             const float* __restrict__ w1,
                                             const float* __restrict__ w2,
                                             const float* __restrict__ cw1,
                                             ushort* __restrict__ o) {
  if (blockIdx.x < 8192) {
    int idx = blockIdx.x * 256 + threadIdx.x;   // over B*D*E = 2M
    int e = idx & (EE - 1);
    int d = (idx >> 8) & (DD - 1);
    int b = idx >> 18;
    float p = fe[d * EE + e];
    int code = d + 1;
    #pragma unroll
    for (int bit = 0; bit < NBITS; bit++) {
      float cb = (float)((code >> (NBITS - 1 - bit)) & 1) - 0.5f;
      p += cb * binary_w[e * NBITS + bit];
    }
    kv_bf[idx] = f2bf(x[b * DD + d] * value_w[e] + value_b[e] + p);
    h[idx] = p;
  } else if (blockIdx.x < 8200) {
    __shared__ float red[256];
    int b = blockIdx.x - 8192, t = threadIdx.x;
    float s = 0.f;
    #pragma unroll
    for (int i = 0; i < 4; i++) s += x[b * DD + t + i * 256];
    red[t] = s; __syncthreads();
    for (int off = 128; off > 0; off >>= 1) {
      if (t < off) red[t] += red[t + off];
      __syncthreads();
    }
    float total = red[0];
    float ta = tanhf(film_alpha[0]);
    float fa = film_a[0];
    #pragma unroll
    for (int i = 0; i < 4; i++) {
      int d = t + i * 256;
      float xn = (total - x[b * DD + d]) / 1023.0f;
      float qs = 1.0f + ta * tanhf(fa * xn);
      qs = fminf(fmaxf(qs, 0.7f), 1.3f);
      qscale[b * DD + d] = qs;
    }
  } else {
    int i = (int)(blockIdx.x - 8200) * 256 + threadIdx.x;
    float v;
    if (i < 65536) v = qw[i];
    else if (i < 131072) v = kw[i - 65536];
    else if (i < 196608) v = vw[i - 131072];
    else if (i < 327680) v = w1[i - 196608];
    else if (i < 458752) v = w2[i - 327680];
    else v = cw1[i - 458752];
    o[i] = f2bf(v);
  }
}

// ---------------- MFMA GEMM for KV projection (unchanged) ----------------
template <int KT>
__global__ __launch_bounds__(512) void kvgemm_k(const ushort* __restrict__ A,
                                                const ushort* __restrict__ Bw,
                                                ushort* __restrict__ C,
                                                ushort* __restrict__ C2) {
  __shared__ ushort As[2][128 * 64];
  __shared__ ushort Bs[2][64 * 64];
  int tid = threadIdx.x;
  int w = tid >> 6, lane = tid & 63;
  int c = lane & 15, g = lane >> 4;
  int wr = w >> 1, wc = w & 1;
  int lr = lane >> 3, lsl = lane & 7;

  const ushort* Ab = A + (size_t)(blockIdx.y * 128) * KT;
  const ushort* Bb = Bw + (size_t)(blockIdx.x * 64) * KT;

  f4 acc[2][2] = {};
  const int NT = KT / 64;

#define STAGE(buf, kt) do {                                                                   \
    _Pragma("unroll")                                                                         \
    for (int j = 0; j < 2; j++) {                                                             \
      int rl = j * 64 + w * 8 + lr;                                                           \
      int slot = lsl ^ (rl & 7);                                                              \
      async_copy16(&As[buf][(j * 64 + w * 8) * 64], Ab + (size_t)rl * KT + (kt) * 64 + slot * 8); \
    }                                                                                         \
    { int rl = w * 8 + lr; int slot = lsl ^ (rl & 7);                                         \
      async_copy16(&Bs[buf][(w * 8) * 64], Bb + (size_t)rl * KT + (kt) * 64 + slot * 8); }    \
  } while (0)

  STAGE(0, 0);
  __syncthreads();

  #pragma unroll
  for (int kt = 0; kt < NT; kt++) {
    int cur = kt & 1;
    if (kt + 1 < NT) STAGE(cur ^ 1, kt + 1);
    #pragma unroll
    for (int ks2 = 0; ks2 < 2; ks2++) {
      short8 af[2], bf_[2];
      #pragma unroll
      for (int mi = 0; mi < 2; mi++) {
        int rowl = wr * 32 + mi * 16 + c;
        int slot = (ks2 * 4 + g) ^ (rowl & 7);
        af[mi] = *(const short8*)&As[cur][rowl * 64 + slot * 8];
      }
      #pragma unroll
      for (int ni = 0; ni < 2; ni++) {
        int rowl = wc * 32 + ni * 16 + c;
        int slot = (ks2 * 4 + g) ^ (rowl & 7);
        bf_[ni] = *(const short8*)&Bs[cur][rowl * 64 + slot * 8];
      }
      #pragma unroll
      for (int mi = 0; mi < 2; mi++)
        #pragma unroll
        for (int ni = 0; ni < 2; ni++)
          acc[mi][ni] = __builtin_amdgcn_mfma_f32_16x16x32_bf16(af[mi], bf_[ni], acc[mi][ni], 0, 0, 0);
    }
    __syncthreads();
  }
#undef STAGE

  int m0 = blockIdx.y * 128 + wr * 32;
  int n0 = blockIdx.x * 64 + wc * 32;
  #pragma unroll
  for (int mi = 0; mi < 2; mi++) {
    #pragma unroll
    for (int ni = 0; ni < 2; ni++) {
      #pragma unroll
      for (int r = 0; r < 4; r++) {
        int row = m0 + mi * 16 + 4 * g + r;
        int col = n0 + ni * 16 + c;
        float v = acc[mi][ni][r];
        int bI = row >> 10, dI = row & 1023;
        if (col < 256) {
          int hI = col >> 5, eI = col & 31;
          C[(((size_t)(bI * HH + hI)) * DD + dI) * HDD + eI] = f2bf(v);
        } else {
          int ch = col - 256;
          int hI = ch >> 5, eI = ch & 31;
          C2[(((size_t)(bI * HH + hI)) * HDD + eI) * DD + dI] = f2bf(v);
        }
      }
    }
  }
}

// ---------------- megakernel v2: 512 blocks x 16 rows, 8 waves (wave = head) ----------------
// LDS 46 KB. __launch_bounds__(512, 2): empirically this toolchain allocates
// VGPR = 256/arg (r16: arg=2 -> 128 VGPR; r18: arg=4 -> 64 VGPR + 425 MB spill).
// Single-group kernel needs ~110 live regs -> fits 128 with zero spill;
// 128 VGPR = 4 waves/SIMD = 2 blocks/CU (2x r16's TLP).
__global__ __launch_bounds__(512, 2) void mega_k(const float* __restrict__ h0,
                                              const ushort* __restrict__ qwb,
                                              const float* __restrict__ qscale,
                                              const ushort* __restrict__ Kbf,
                                              const ushort* __restrict__ Vtb,
                                              const float* __restrict__ gamma_attn,
                                              const float* __restrict__ strength_p,
                                              const float* __restrict__ lnw,
                                              const float* __restrict__ lnb,
                                              const ushort* __restrict__ w1b,
                                              const float* __restrict__ fb1,
                                              const ushort* __restrict__ w2b,
                                              const float* __restrict__ fb2,
                                              const float* __restrict__ gamma_ffn,
                                              const float* __restrict__ clnw,
                                              const float* __restrict__ clnb,
                                              const ushort* __restrict__ cw1b,
                                              const float* __restrict__ cb1,
                                              const float* __restrict__ cw2,
                                              const float* __restrict__ cb2,
                                              float* __restrict__ out) {
  __shared__ __align__(16) float hs[16][256];       // persistent fp32 residual (16 KB)
  __shared__ __align__(16) ushort S1[16 * 256];     // time-shared: hsb / ybs (8 KB)
  __shared__ __align__(16) char Rb[22528];          // time-shared: Pl / upd / t-half / red

  ushort (*Pl)[16][88] = (ushort (*)[16][88])Rb;    // [8][16][88] = 22528 B
  float (*upd)[260]    = (float (*)[260])Rb;        // 16*260*4 = 16640 B
  ushort* tt           = (ushort*)Rb;               // t half: [16][256] bf16 = 8192 B
  float (*red)[16]     = (float (*)[16])Rb;         // tail reduce [8][16]

  int tid = threadIdx.x;
  int w = tid >> 6, lane = tid & 63;
  int c = lane & 15, g = lane >> 4;
  int lid = ((blockIdx.x & 7) << 6) + (blockIdx.x >> 3);   // batch == XCD
  int b = lid >> 6;
  int chunk = lid & 63;
  int q0 = chunk * 16;
  int hh = w;
  int bh = b * HH + hh;
  int dtile = chunk >> 2;
  float ss = fmaxf(strength_p[0], 0.f) * exp2f(-(float)hh / 8.0f);
  const float L2E = 1.4426950408889634f;

  // ---- stage hs (fp32) + hsb (bf16, XOR-swizzled) : 1024 float4 over 512 threads ----
  #pragma unroll
  for (int i = 0; i < 2; i++) {
    int j = tid + i * 512;          // 0..1023
    int row = j >> 6;
    int col = (j & 63) * 4;
    const float4 v = *(const float4*)&h0[((size_t)(b * DD + q0 + row)) * EE + col];
    *(float4*)&hs[row][col] = v;
    ushort4 o;
    o.x = f2bf(v.x); o.y = f2bf(v.y); o.z = f2bf(v.z); o.w = f2bf(v.w);
    int sp = (col >> 3) ^ (row & 7);
    *(ushort4*)&S1[row * 256 + sp * 8 + (col & 7)] = o;
  }
  __syncthreads();

  #pragma unroll 1
  for (int layer = 0; layer < 2; layer++) {
    // ---- fused Q projection: 16 rows, this wave's head, K=256 ----
    short8 qf;
    {
      f4 qa0 = {0.f, 0.f, 0.f, 0.f}, qa1 = {0.f, 0.f, 0.f, 0.f};
      int rowA = c;
      const ushort* Bb0 = qwb + ((size_t)(hh * HDD + c)) * EE + 8 * g;
      const ushort* Bb1 = Bb0 + (size_t)16 * EE;
      #pragma unroll
      for (int kk = 0; kk < 8; kk++) {
        int sp = (kk * 4 + g) ^ (rowA & 7);
        short8 a  = *(const short8*)&S1[rowA * 256 + sp * 8];
        short8 b0 = *(const short8*)(Bb0 + kk * 32);
        short8 b1 = *(const short8*)(Bb1 + kk * 32);
        qa0 = __builtin_amdgcn_mfma_f32_16x16x32_bf16(a, b0, qa0, 0, 0, 0);
        qa1 = __builtin_amdgcn_mfma_f32_16x16x32_bf16(a, b1, qa1, 0, 0, 0);
      }
      const float4 qsv = *(const float4*)&qscale[b * DD + q0 + 4 * g];
      float qs[4] = {qsv.x, qsv.y, qsv.z, qsv.w};
      #pragma unroll
      for (int r = 0; r < 4; r++) {
        float sc = qs[r] * 0.17677669529663687f;
        Pl[w][4 * g + r][c]      = f2bf(qa0[r] * sc);
        Pl[w][4 * g + r][16 + c] = f2bf(qa1[r] * sc);
      }
      qf = *(const short8*)&Pl[w][c][8 * g];   // wave-internal in-order
    }

    // ---- banded attention, static softmax ----
    int Wi = (ss > 1e-8f) ? (int)fminf(14.0f / ss, 1.0e6f) : 1000000;
    int hi = min(15, (q0 + 15 + Wi) >> 6);
    int tlo = q0 - 63 - Wi;
    int lo = (tlo <= 0) ? 0 : ((tlo + 63) >> 6);

    f4 oacc0 = {0.f, 0.f, 0.f, 0.f};
    f4 oacc1 = {0.f, 0.f, 0.f, 0.f};
    float lpart = 0.f;
    int qg = q0 + c;
    const ushort* Kb0 = Kbf + (((size_t)bh * DD + c) << 5) + (g << 3);
    const ushort* Vb0 = Vtb + ((size_t)(bh * HDD + c)) * DD + (g << 3);

    #pragma unroll 1
    for (int ks = lo; ks <= hi; ks++) {
      short8 kf[4];
      #pragma unroll
      for (int t = 0; t < 4; t++)
        kf[t] = *(const short8*)(Kb0 + (((size_t)(ks * 64 + t * 16)) << 5));
      const ushort* vb = Vb0 + ks * 64;
      short8 va0 = *(const short8*)(vb);
      short8 va1 = *(const short8*)(vb + 32);
      short8 vc0 = *(const short8*)(vb + (size_t)16 * DD);
      short8 vc1 = *(const short8*)(vb + (size_t)16 * DD + 32);
      f4 z = {0.f, 0.f, 0.f, 0.f};
      f4 sa[4];
      #pragma unroll
      for (int t = 0; t < 4; t++)
        sa[t] = __builtin_amdgcn_mfma_f32_16x16x32_bf16(kf[t], qf, z, 0, 0, 0);
      float s[16];
      if (ks == dtile) {
        #pragma unroll
        for (int t = 0; t < 4; t++) {
          #pragma unroll
          for (int r = 0; r < 4; r++) {
            int k = ks * 64 + t * 16 + 4 * g + r;
            float ad = fabsf((float)(qg - k));
            s[t * 4 + r] = (k == qg) ? -1e30f : fmaf(-ss, ad, sa[t][r]);
          }
        }
      } else {
        float sgn = (ks > dtile) ? -ss : ss;   // bias = sgn*(k - qg) <= 0
        int kb2 = ks * 64 + 4 * g - qg;
        #pragma unroll
        for (int t = 0; t < 4; t++) {
          #pragma unroll
          for (int r = 0; r < 4; r++) {
            float dk = (float)(kb2 + t * 16 + r);
            s[t * 4 + r] = fmaf(sgn, dk, sa[t][r]);
          }
        }
      }
      #pragma unroll
      for (int i = 0; i < 16; i++) {
        float p = exp2f(s[i] * L2E);
        s[i] = p;
        lpart += p;
      }
      #pragma unroll
      for (int t = 0; t < 4; t++) {
        uint2 u;
        u.x = __builtin_amdgcn_perm(__float_as_uint(s[t * 4 + 1]), __float_as_uint(s[t * 4 + 0]), 0x07060302u);
        u.y = __builtin_amdgcn_perm(__float_as_uint(s[t * 4 + 3]), __float_as_uint(s[t * 4 + 2]), 0x07060302u);
        *(uint2*)&Pl[w][c][t * 16 + 4 * g] = u;
      }
      short8 pa0 = *(const short8*)&Pl[w][c][8 * g];
      short8 pa1 = *(const short8*)&Pl[w][c][32 + 8 * g];
      oacc0 = __builtin_amdgcn_mfma_f32_16x16x32_bf16(pa0, va0, oacc0, 0, 0, 0);
      oacc1 = __builtin_amdgcn_mfma_f32_16x16x32_bf16(pa0, vc0, oacc1, 0, 0, 0);
      oacc0 = __builtin_amdgcn_mfma_f32_16x16x32_bf16(pa1, va1, oacc0, 0, 0, 0);
      oacc1 = __builtin_amdgcn_mfma_f32_16x16x32_bf16(pa1, vc1, oacc1, 0, 0, 0);
    }
    lpart += __shfl_xor(lpart, 16);
    lpart += __shfl_xor(lpart, 32);
    float linv = 1.0f / lpart;
    __syncthreads();   // Pl dead everywhere -> R becomes upd

    // ---- deposit gamma_attn * O / l into upd ----
    #pragma unroll
    for (int r = 0; r < 4; r++) {
      float li = __shfl(linv, 4 * g + r);
      int row = 4 * g + r;
      int e0 = hh * HDD + c, e1 = hh * HDD + 16 + c;
      upd[row][e0] = gamma_attn[e0] * oacc0[r] * li;
      upd[row][e1] = gamma_attn[e1] * oacc1[r] * li;
    }
    __syncthreads();

    // ---- residual + LayerNorm -> ybs (S1); wave w rows 2w, 2w+1 ----
    #pragma unroll
    for (int rr = 0; rr < 2; rr++) {
      int row = 2 * w + rr;
      const float4 hv = *(const float4*)&hs[row][4 * lane];
      const float4 uv = *(const float4*)&upd[row][4 * lane];
      float4 v;
      v.x = hv.x + uv.x; v.y = hv.y + uv.y; v.z = hv.z + uv.z; v.w = hv.w + uv.w;
      *(float4*)&hs[row][4 * lane] = v;
      float s  = v.x + v.y + v.z + v.w;
      float s2 = v.x * v.x + v.y * v.y + v.z * v.z + v.w * v.w;
      #pragma unroll
      for (int off = 32; off; off >>= 1) {
        s  += __shfl_xor(s, off);
        s2 += __shfl_xor(s2, off);
      }
      float mean = s * (1.0f / EE);
      float var = s2 * (1.0f / EE) - mean * mean;
      float rs = rsqrtf(var + 1e-5f);
      const float4 wv = *(const float4*)&lnw[4 * lane];
      const float4 bv = *(const float4*)&lnb[4 * lane];
      ushort4 o;
      o.x = f2bf((v.x - mean) * rs * wv.x + bv.x);
      o.y = f2bf((v.y - mean) * rs * wv.y + bv.y);
      o.z = f2bf((v.z - mean) * rs * wv.z + bv.z);
      o.w = f2bf((v.w - mean) * rs * wv.w + bv.w);
      int sp = (lane >> 1) ^ (row & 7);
      *(ushort4*)&S1[row * 256 + sp * 8 + (lane & 1) * 4] = o;
    }
    __syncthreads();   // ybs + hs(post-attn) complete; upd dead -> R becomes t

    // ---- FFN: two 256-col halves; t half staged in R ----
    f4 acc2[2] = {};
    #pragma unroll 1
    for (int H = 0; H < 2; H++) {
      f4 acc1[2] = {};
      #pragma unroll
      for (int kstep = 0; kstep < 8; kstep++) {
        int row = c;
        int sp = (kstep * 4 + g) ^ (row & 7);
        short8 af = *(const short8*)&S1[row * 256 + sp * 8];
        #pragma unroll
        for (int ni = 0; ni < 2; ni++) {
          int col = H * 256 + w * 32 + ni * 16 + c;
          short8 bf_ = *(const short8*)(w1b + (size_t)col * EE + kstep * 32 + 8 * g);
          acc1[ni] = __builtin_amdgcn_mfma_f32_16x16x32_bf16(af, bf_, acc1[ni], 0, 0, 0);
        }
      }
      // GELU -> t (bf16, swizzled)
      #pragma unroll
      for (int ni = 0; ni < 2; ni++) {
        #pragma unroll
        for (int r = 0; r < 4; r++) {
          int row = 4 * g + r;
          int colH = w * 32 + ni * 16 + c;
          float v = acc1[ni][r] + fb1[H * 256 + colH];
          float gl = 0.5f * v * (1.0f + erff(v * 0.70710678118654752f));
          int sp = (colH >> 3) ^ (row & 7);
          tt[row * 256 + sp * 8 + (colH & 7)] = f2bf(gl);
        }
      }
      __syncthreads();   // t(H) ready
      #pragma unroll
      for (int kstep = 0; kstep < 8; kstep++) {
        int row = c;
        int sp = (kstep * 4 + g) ^ (row & 7);
        short8 af = *(const short8*)&tt[row * 256 + sp * 8];
        #pragma unroll
        for (int ni = 0; ni < 2; ni++) {
          int col = w * 32 + ni * 16 + c;
          short8 bf_ = *(const short8*)(w2b + (size_t)col * 512 + H * 256 + kstep * 32 + 8 * g);
          acc2[ni] = __builtin_amdgcn_mfma_f32_16x16x32_bf16(af, bf_, acc2[ni], 0, 0, 0);
        }
      }
      __syncthreads();   // t reads done (safe to overwrite next half)
    }
    // FFN residual into hs (each lane owns unique (row,col))
    #pragma unroll
    for (int ni = 0; ni < 2; ni++) {
      #pragma unroll
      for (int r = 0; r < 4; r++) {
        int row = 4 * g + r;
        int col = w * 32 + ni * 16 + c;
        float v = acc2[ni][r] + fb2[col];
        hs[row][col] += gamma_ffn[col] * v;
      }
    }
    __syncthreads();   // hs final for this layer

    // ---- refresh hsb for next layer's Q-proj ----
    if (layer == 0) {
      #pragma unroll
      for (int i = 0; i < 2; i++) {
        int j = tid + i * 512;
        int row = j >> 6;
        int col = (j & 63) * 4;
        const float4 v = *(const float4*)&hs[row][col];
        ushort4 o;
        o.x = f2bf(v.x); o.y = f2bf(v.y); o.z = f2bf(v.z); o.w = f2bf(v.w);
        int sp = (col >> 3) ^ (row & 7);
        *(ushort4*)&S1[row * 256 + sp * 8 + (col & 7)] = o;
      }
      __syncthreads();
    }
  }

  // ---- correction head: LN -> GEMM(+b1, GELU) -> dot w2 -> out ----
  #pragma unroll
  for (int rr = 0; rr < 2; rr++) {
    int row = 2 * w + rr;
    const float4 v = *(const float4*)&hs[row][4 * lane];
    float s  = v.x + v.y + v.z + v.w;
    float s2 = v.x * v.x + v.y * v.y + v.z * v.z + v.w * v.w;
    #pragma unroll
    for (int off = 32; off; off >>= 1) {
      s  += __shfl_xor(s, off);
      s2 += __shfl_xor(s2, off);
    }
    float mean = s * (1.0f / EE);
    float var = s2 * (1.0f / EE) - mean * mean;
    float rs = rsqrtf(var + 1e-5f);
    const float4 wv = *(const float4*)&clnw[4 * lane];
    const float4 bv = *(const float4*)&clnb[4 * lane];
    ushort4 o;
    o.x = f2bf((v.x - mean) * rs * wv.x + bv.x);
    o.y = f2bf((v.y - mean) * rs * wv.y + bv.y);
    o.z = f2bf((v.z - mean) * rs * wv.z + bv.z);
    o.w = f2bf((v.w - mean) * rs * wv.w + bv.w);
    int sp = (lane >> 1) ^ (row & 7);
    *(ushort4*)&S1[row * 256 + sp * 8 + (lane & 1) * 4] = o;
  }
  __syncthreads();

  f4 acc[2] = {};
  #pragma unroll
  for (int kstep = 0; kstep < 8; kstep++) {
    int row = c;
    int sp = (kstep * 4 + g) ^ (row & 7);
    short8 af = *(const short8*)&S1[row * 256 + sp * 8];
    #pragma unroll
    for (int ni = 0; ni < 2; ni++) {
      int col = w * 32 + ni * 16 + c;
      short8 bf_ = *(const short8*)(cw1b + (size_t)col * EE + kstep * 32 + 8 * g);
      acc[ni] = __builtin_amdgcn_mfma_f32_16x16x32_bf16(af, bf_, acc[ni], 0, 0, 0);
    }
  }
  float b1v[2], w2v[2];
  #pragma unroll
  for (int ni = 0; ni < 2; ni++) {
    int col = w * 32 + ni * 16 + c;
    b1v[ni] = cb1[col];
    w2v[ni] = cw2[col];
  }
  __syncthreads();   // S1 reads done block-wide before red overlays R
  #pragma unroll
  for (int r = 0; r < 4; r++) {
    float s = 0.f;
    #pragma unroll
    for (int ni = 0; ni < 2; ni++) {
      float v = acc[ni][r] + b1v[ni];
      float gl = 0.5f * v * (1.0f + erff(v * 0.70710678118654752f));
      s += gl * w2v[ni];
    }
    s += __shfl_xor(s, 1);
    s += __shfl_xor(s, 2);
    s += __shfl_xor(s, 4);
    s += __shfl_xor(s, 8);
    if (c == 0) red[w][4 * g + r] = s;
  }
  __syncthreads();
  if (tid < 16) {
    float s = 0.f;
    #pragma unroll
    for (int ww = 0; ww < 8; ww++) s += red[ww][tid];
    out[(b << 10) + q0 + tid] = s + cb2[0];
  }
}

extern "C" void kernel_launch(void* const* d_in, const int* in_sizes, int n_in,
                              void* d_out, int out_size, void* d_ws, size_t ws_size,
                              hipStream_t stream) {
  const float* x            = (const float*)d_in[0];
  const float* value_w      = (const float*)d_in[1];
  const float* value_b      = (const float*)d_in[2];
  const float* feature_embed= (const float*)d_in[3];
  const float* binary_w     = (const float*)d_in[4];
  const float* qw           = (const float*)d_in[5];
  const float* kw           = (const float*)d_in[6];
  const float* vw           = (const float*)d_in[7];
  const float* film_alpha   = (const float*)d_in[8];
  const float* film_a       = (const float*)d_in[9];
  const float* ln1_w        = (const float*)d_in[10];
  const float* ln1_b        = (const float*)d_in[11];
  const float* ffn_w1       = (const float*)d_in[12];
  const float* ffn_b1       = (const float*)d_in[13];
  const float* ffn_w2       = (const float*)d_in[14];
  const float* ffn_b2       = (const float*)d_in[15];
  const float* gamma_attn   = (const float*)d_in[16];
  const float* gamma_ffn    = (const float*)d_in[17];
  const float* corr_ln_w    = (const float*)d_in[18];
  const float* corr_ln_b    = (const float*)d_in[19];
  const float* corr_w1      = (const float*)d_in[20];
  const float* corr_b1      = (const float*)d_in[21];
  const float* corr_w2      = (const float*)d_in[22];
  const float* corr_b2      = (const float*)d_in[23];
  const float* alibi_strength=(const float*)d_in[24];

  const size_t ME = (size_t)BD * DD * EE;   // 2M
  float* ws = (float*)d_ws;
  float* qscale = ws;                       // 8192 f
  float* hb     = qscale + BD * DD;         // 2M f
  ushort* kv_bf = (ushort*)(hb + ME);       // 2M us
  ushort* Kbf   = kv_bf + ME;               // 2M us
  ushort* Vtb   = Kbf + ME;                 // 2M us
  ushort* wbf   = Vtb + ME;                 // 524288 us
  ushort* qwb   = wbf;
  ushort* kwb   = wbf + 65536;              // kw rows 0-255, vw rows 256-511 (contiguous)
  ushort* w1b   = wbf + 196608;
  ushort* w2b   = wbf + 327680;
  ushort* cw1b  = wbf + 458752;

  const int M = BD * DD;   // 8192

  k_pro<<<8192 + 8 + 2048, 256, 0, stream>>>(x, value_w, value_b, feature_embed, binary_w,
                                             kv_bf, hb,
                                             film_alpha, film_a, qscale,
                                             qw, kw, vw, ffn_w1, ffn_w2, corr_w1, wbf);

  kvgemm_k<256><<<dim3(512 / 64, M / 128), 512, 0, stream>>>(kv_bf, kwb, Kbf, Vtb);

  mega_k<<<dim3(512), 512, 0, stream>>>(hb, qwb, qscale, Kbf, Vtb,
                                        gamma_attn, alibi_strength,
                                        ln1_w, ln1_b,
                                        w1b, ffn_b1, w2b, ffn_b2, gamma_ffn,
                                        corr_ln_w, corr_ln_b,
                                        cw1b, corr_b1, corr_w2, corr_b2,
                                        (float*)d_out);
}

// Round 20
// 127.380 us; speedup vs baseline: 3.1782x; 1.3739x over previous
//
#include <hip/hip_runtime.h>
#include <math.h>

#define BD 8
#define DD 1024
#define EE 256
#define HH 8
#define HDD 32
#define NBITS 11

typedef __attribute__((ext_vector_type(8))) short short8;
typedef __attribute__((ext_vector_type(4))) float f4;

__device__ __forceinline__ ushort f2bf(float f) {
  unsigned u = __float_as_uint(f);
  u += 0x7fffu + ((u >> 16) & 1u);
  return (ushort)(u >> 16);
}
__device__ __forceinline__ void async_copy16(ushort* lds, const ushort* g) {
  __builtin_amdgcn_global_load_lds((const __attribute__((address_space(1))) void*)g,
                                   (__attribute__((address_space(3))) void*)lds, 16, 0, 0);
}

// ---------------- fused prologue ----------------
// blocks 0..8191: kv/h init (pos inline); 8192..8199: qscale; 8200..10247: weight bf16 conv
__global__ __launch_bounds__(256) void k_pro(const float* __restrict__ x,
                                             const float* __restrict__ value_w,
                                             const float* __restrict__ value_b,
                                             const float* __restrict__ fe,
                                             const float* __restrict__ binary_w,
                                             ushort* __restrict__ kv_bf,
                                             float* __restrict__ h,
                                             const float* __restrict__ film_alpha,
                                             const float* __restrict__ film_a,
                                             float* __restrict__ qscale,
                                             const float* __restrict__ qw,
                                             const float* __restrict__ kw,
                                             const float* __restrict__ vw,
                                             const float* __restrict__ w1,
                                             const float* __restrict__ w2,
                                             const float* __restrict__ cw1,
                                             ushort* __restrict__ o) {
  if (blockIdx.x < 8192) {
    int idx = blockIdx.x * 256 + threadIdx.x;   // over B*D*E = 2M
    int e = idx & (EE - 1);
    int d = (idx >> 8) & (DD - 1);
    int b = idx >> 18;
    float p = fe[d * EE + e];
    int code = d + 1;
    #pragma unroll
    for (int bit = 0; bit < NBITS; bit++) {
      float cb = (float)((code >> (NBITS - 1 - bit)) & 1) - 0.5f;
      p += cb * binary_w[e * NBITS + bit];
    }
    kv_bf[idx] = f2bf(x[b * DD + d] * value_w[e] + value_b[e] + p);
    h[idx] = p;
  } else if (blockIdx.x < 8200) {
    __shared__ float red[256];
    int b = blockIdx.x - 8192, t = threadIdx.x;
    float s = 0.f;
    #pragma unroll
    for (int i = 0; i < 4; i++) s += x[b * DD + t + i * 256];
    red[t] = s; __syncthreads();
    for (int off = 128; off > 0; off >>= 1) {
      if (t < off) red[t] += red[t + off];
      __syncthreads();
    }
    float total = red[0];
    float ta = tanhf(film_alpha[0]);
    float fa = film_a[0];
    #pragma unroll
    for (int i = 0; i < 4; i++) {
      int d = t + i * 256;
      float xn = (total - x[b * DD + d]) / 1023.0f;
      float qs = 1.0f + ta * tanhf(fa * xn);
      qs = fminf(fmaxf(qs, 0.7f), 1.3f);
      qscale[b * DD + d] = qs;
    }
  } else {
    int i = (int)(blockIdx.x - 8200) * 256 + threadIdx.x;
    float v;
    if (i < 65536) v = qw[i];
    else if (i < 131072) v = kw[i - 65536];
    else if (i < 196608) v = vw[i - 131072];
    else if (i < 327680) v = w1[i - 196608];
    else if (i < 458752) v = w2[i - 327680];
    else v = cw1[i - 458752];
    o[i] = f2bf(v);
  }
}

// ---------------- MFMA GEMM for KV projection (unchanged) ----------------
template <int KT>
__global__ __launch_bounds__(512) void kvgemm_k(const ushort* __restrict__ A,
                                                const ushort* __restrict__ Bw,
                                                ushort* __restrict__ C,
                                                ushort* __restrict__ C2) {
  __shared__ ushort As[2][128 * 64];
  __shared__ ushort Bs[2][64 * 64];
  int tid = threadIdx.x;
  int w = tid >> 6, lane = tid & 63;
  int c = lane & 15, g = lane >> 4;
  int wr = w >> 1, wc = w & 1;
  int lr = lane >> 3, lsl = lane & 7;

  const ushort* Ab = A + (size_t)(blockIdx.y * 128) * KT;
  const ushort* Bb = Bw + (size_t)(blockIdx.x * 64) * KT;

  f4 acc[2][2] = {};
  const int NT = KT / 64;

#define STAGE(buf, kt) do {                                                                   \
    _Pragma("unroll")                                                                         \
    for (int j = 0; j < 2; j++) {                                                             \
      int rl = j * 64 + w * 8 + lr;                                                           \
      int slot = lsl ^ (rl & 7);                                                              \
      async_copy16(&As[buf][(j * 64 + w * 8) * 64], Ab + (size_t)rl * KT + (kt) * 64 + slot * 8); \
    }                                                                                         \
    { int rl = w * 8 + lr; int slot = lsl ^ (rl & 7);                                         \
      async_copy16(&Bs[buf][(w * 8) * 64], Bb + (size_t)rl * KT + (kt) * 64 + slot * 8); }    \
  } while (0)

  STAGE(0, 0);
  __syncthreads();

  #pragma unroll
  for (int kt = 0; kt < NT; kt++) {
    int cur = kt & 1;
    if (kt + 1 < NT) STAGE(cur ^ 1, kt + 1);
    #pragma unroll
    for (int ks2 = 0; ks2 < 2; ks2++) {
      short8 af[2], bf_[2];
      #pragma unroll
      for (int mi = 0; mi < 2; mi++) {
        int rowl = wr * 32 + mi * 16 + c;
        int slot = (ks2 * 4 + g) ^ (rowl & 7);
        af[mi] = *(const short8*)&As[cur][rowl * 64 + slot * 8];
      }
      #pragma unroll
      for (int ni = 0; ni < 2; ni++) {
        int rowl = wc * 32 + ni * 16 + c;
        int slot = (ks2 * 4 + g) ^ (rowl & 7);
        bf_[ni] = *(const short8*)&Bs[cur][rowl * 64 + slot * 8];
      }
      #pragma unroll
      for (int mi = 0; mi < 2; mi++)
        #pragma unroll
        for (int ni = 0; ni < 2; ni++)
          acc[mi][ni] = __builtin_amdgcn_mfma_f32_16x16x32_bf16(af[mi], bf_[ni], acc[mi][ni], 0, 0, 0);
    }
    __syncthreads();
  }
#undef STAGE

  int m0 = blockIdx.y * 128 + wr * 32;
  int n0 = blockIdx.x * 64 + wc * 32;
  #pragma unroll
  for (int mi = 0; mi < 2; mi++) {
    #pragma unroll
    for (int ni = 0; ni < 2; ni++) {
      #pragma unroll
      for (int r = 0; r < 4; r++) {
        int row = m0 + mi * 16 + 4 * g + r;
        int col = n0 + ni * 16 + c;
        float v = acc[mi][ni][r];
        int bI = row >> 10, dI = row & 1023;
        if (col < 256) {
          int hI = col >> 5, eI = col & 31;
          C[(((size_t)(bI * HH + hI)) * DD + dI) * HDD + eI] = f2bf(v);
        } else {
          int ch = col - 256;
          int hI = ch >> 5, eI = ch & 31;
          C2[(((size_t)(bI * HH + hI)) * HDD + eI) * DD + dI] = f2bf(v);
        }
      }
    }
  }
}

// ---------------- megakernel: both layers + correction head, row-local ----------------
// 256 blocks x 512 threads (32 rows, wave = head, 2 query-groups of 16) — the proven
// r16 config (131.7 us total). Changes this round: window threshold 14->10 (band -29%,
// error bound ~1e-6 in h), s_setprio(1) around attention MFMA clusters (T5).
__global__ __launch_bounds__(512, 2) void mega_k(const float* __restrict__ h0,
                                              const ushort* __restrict__ qwb,
                                              const float* __restrict__ qscale,
                                              const ushort* __restrict__ Kbf,
                                              const ushort* __restrict__ Vtb,
                                              const float* __restrict__ gamma_attn,
                                              const float* __restrict__ strength_p,
                                              const float* __restrict__ lnw,
                                              const float* __restrict__ lnb,
                                              const ushort* __restrict__ w1b,
                                              const float* __restrict__ fb1,
                                              const ushort* __restrict__ w2b,
                                              const float* __restrict__ fb2,
                                              const float* __restrict__ gamma_ffn,
                                              const float* __restrict__ clnw,
                                              const float* __restrict__ clnb,
                                              const ushort* __restrict__ cw1b,
                                              const float* __restrict__ cb1,
                                              const float* __restrict__ cw2,
                                              const float* __restrict__ cb2,
                                              float* __restrict__ out) {
  __shared__ __align__(16) float hs[32][256];       // persistent fp32 residual (32 KB)
  __shared__ __align__(16) ushort S1[32 * 256];     // time-shared: hsb / ybs (16 KB)
  __shared__ __align__(16) char Rb[33280];          // time-shared: Pl / upd / t-half / red

  ushort (*Pl)[16][88] = (ushort (*)[16][88])Rb;    // [8][16][88] = 22528 B
  float (*upd)[260]    = (float (*)[260])Rb;        // 32*260*4 = 33280 B
  ushort* tt           = (ushort*)Rb;               // t half: [32][256] bf16 = 16384 B
  float (*red)[32]     = (float (*)[32])Rb;         // tail reduce [8][32]

  int tid = threadIdx.x;
  int w = tid >> 6, lane = tid & 63;
  int c = lane & 15, g = lane >> 4;
  int lid = ((blockIdx.x & 7) << 5) + (blockIdx.x >> 3);   // batch == XCD
  int b = lid >> 5;
  int chunk = lid & 31;
  int q0 = chunk * 32;
  int hh = w;
  int bh = b * HH + hh;
  int dtile = q0 >> 6;
  float ss = fmaxf(strength_p[0], 0.f) * exp2f(-(float)hh / 8.0f);
  const float L2E = 1.4426950408889634f;

  // ---- stage hs (fp32) + hsb (bf16, XOR-swizzled) ----
  #pragma unroll
  for (int i = 0; i < 4; i++) {
    int j = tid + i * 512;          // float4 index, 0..2047
    int row = j >> 6;
    int col = (j & 63) * 4;
    const float4 v = *(const float4*)&h0[((size_t)(b * DD + q0 + row)) * EE + col];
    *(float4*)&hs[row][col] = v;
    ushort4 o;
    o.x = f2bf(v.x); o.y = f2bf(v.y); o.z = f2bf(v.z); o.w = f2bf(v.w);
    int sp = (col >> 3) ^ (row & 7);
    *(ushort4*)&S1[row * 256 + sp * 8 + (col & 7)] = o;
  }
  __syncthreads();

  #pragma unroll 1
  for (int layer = 0; layer < 2; layer++) {
    // ---- fused Q projection, both groups ----
    short8 qf[2];
    #pragma unroll
    for (int G = 0; G < 2; G++) {
      f4 qa0 = {0.f, 0.f, 0.f, 0.f}, qa1 = {0.f, 0.f, 0.f, 0.f};
      int rowA = G * 16 + c;
      const ushort* Bb0 = qwb + ((size_t)(hh * HDD + c)) * EE + 8 * g;
      const ushort* Bb1 = Bb0 + (size_t)16 * EE;
      #pragma unroll
      for (int kk = 0; kk < 8; kk++) {
        int sp = (kk * 4 + g) ^ (rowA & 7);
        short8 a  = *(const short8*)&S1[rowA * 256 + sp * 8];
        short8 b0 = *(const short8*)(Bb0 + kk * 32);
        short8 b1 = *(const short8*)(Bb1 + kk * 32);
        qa0 = __builtin_amdgcn_mfma_f32_16x16x32_bf16(a, b0, qa0, 0, 0, 0);
        qa1 = __builtin_amdgcn_mfma_f32_16x16x32_bf16(a, b1, qa1, 0, 0, 0);
      }
      const float4 qsv = *(const float4*)&qscale[b * DD + q0 + G * 16 + 4 * g];
      float qs[4] = {qsv.x, qsv.y, qsv.z, qsv.w};
      #pragma unroll
      for (int r = 0; r < 4; r++) {
        float sc = qs[r] * 0.17677669529663687f;
        Pl[w][4 * g + r][c]      = f2bf(qa0[r] * sc);
        Pl[w][4 * g + r][16 + c] = f2bf(qa1[r] * sc);
      }
      qf[G] = *(const short8*)&Pl[w][c][8 * g];   // wave-internal in-order
    }

    // ---- banded attention, static softmax (thr=10) ----
    int Wi = (ss > 1e-8f) ? (int)fminf(10.0f / ss, 1.0e6f) : 1000000;
    int hi = min(15, (q0 + 31 + Wi) >> 6);
    int tlo = q0 - 63 - Wi;
    int lo = (tlo <= 0) ? 0 : ((tlo + 63) >> 6);

    f4 oacc[2][2] = {};
    float lpart[2] = {0.f, 0.f};
    const ushort* Kb0 = Kbf + (((size_t)bh * DD + c) << 5) + (g << 3);
    const ushort* Vb0 = Vtb + ((size_t)(bh * HDD + c)) * DD + (g << 3);

    #pragma unroll 1
    for (int ks = lo; ks <= hi; ks++) {
      short8 kf[4];
      #pragma unroll
      for (int t = 0; t < 4; t++)
        kf[t] = *(const short8*)(Kb0 + (((size_t)(ks * 64 + t * 16)) << 5));
      const ushort* vb = Vb0 + ks * 64;
      short8 va0 = *(const short8*)(vb);
      short8 va1 = *(const short8*)(vb + 32);
      short8 vc0 = *(const short8*)(vb + (size_t)16 * DD);
      short8 vc1 = *(const short8*)(vb + (size_t)16 * DD + 32);
      float sgn = (ks > dtile) ? -ss : ss;
      #pragma unroll
      for (int G = 0; G < 2; G++) {
        int qg = q0 + G * 16 + c;
        f4 z = {0.f, 0.f, 0.f, 0.f};
        f4 sa[4];
        __builtin_amdgcn_s_setprio(1);
        #pragma unroll
        for (int t = 0; t < 4; t++)
          sa[t] = __builtin_amdgcn_mfma_f32_16x16x32_bf16(kf[t], qf[G], z, 0, 0, 0);
        __builtin_amdgcn_s_setprio(0);
        float s[16];
        if (ks == dtile) {
          #pragma unroll
          for (int t = 0; t < 4; t++) {
            #pragma unroll
            for (int r = 0; r < 4; r++) {
              int k = ks * 64 + t * 16 + 4 * g + r;
              float ad = fabsf((float)(qg - k));
              s[t * 4 + r] = (k == qg) ? -1e30f : fmaf(-ss, ad, sa[t][r]);
            }
          }
        } else {
          int kb2 = ks * 64 + 4 * g - qg;
          #pragma unroll
          for (int t = 0; t < 4; t++) {
            #pragma unroll
            for (int r = 0; r < 4; r++) {
              float dk = (float)(kb2 + t * 16 + r);
              s[t * 4 + r] = fmaf(sgn, dk, sa[t][r]);
            }
          }
        }
        float lp = 0.f;
        #pragma unroll
        for (int i = 0; i < 16; i++) {
          float p = exp2f(s[i] * L2E);
          s[i] = p;
          lp += p;
        }
        lpart[G] += lp;
        #pragma unroll
        for (int t = 0; t < 4; t++) {
          uint2 u;
          u.x = __builtin_amdgcn_perm(__float_as_uint(s[t * 4 + 1]), __float_as_uint(s[t * 4 + 0]), 0x07060302u);
          u.y = __builtin_amdgcn_perm(__float_as_uint(s[t * 4 + 3]), __float_as_uint(s[t * 4 + 2]), 0x07060302u);
          *(uint2*)&Pl[w][c][t * 16 + 4 * g] = u;
        }
        short8 pa0 = *(const short8*)&Pl[w][c][8 * g];
        short8 pa1 = *(const short8*)&Pl[w][c][32 + 8 * g];
        __builtin_amdgcn_s_setprio(1);
        oacc[G][0] = __builtin_amdgcn_mfma_f32_16x16x32_bf16(pa0, va0, oacc[G][0], 0, 0, 0);
        oacc[G][1] = __builtin_amdgcn_mfma_f32_16x16x32_bf16(pa0, vc0, oacc[G][1], 0, 0, 0);
        oacc[G][0] = __builtin_amdgcn_mfma_f32_16x16x32_bf16(pa1, va1, oacc[G][0], 0, 0, 0);
        oacc[G][1] = __builtin_amdgcn_mfma_f32_16x16x32_bf16(pa1, vc1, oacc[G][1], 0, 0, 0);
        __builtin_amdgcn_s_setprio(0);
      }
    }
    float linv[2];
    #pragma unroll
    for (int G = 0; G < 2; G++) {
      lpart[G] += __shfl_xor(lpart[G], 16);
      lpart[G] += __shfl_xor(lpart[G], 32);
      linv[G] = 1.0f / lpart[G];
    }
    __syncthreads();   // Pl dead everywhere -> R becomes upd

    // ---- deposit gamma_attn * O / l into upd ----
    #pragma unroll
    for (int G = 0; G < 2; G++) {
      #pragma unroll
      for (int r = 0; r < 4; r++) {
        float li = __shfl(linv[G], 4 * g + r);
        int row = G * 16 + 4 * g + r;
        int e0 = hh * HDD + c, e1 = hh * HDD + 16 + c;
        upd[row][e0] = gamma_attn[e0] * oacc[G][0][r] * li;
        upd[row][e1] = gamma_attn[e1] * oacc[G][1][r] * li;
      }
    }
    __syncthreads();

    // ---- residual + LayerNorm -> ybs (S1); wave w rows 4w..4w+3 ----
    #pragma unroll
    for (int rr = 0; rr < 4; rr++) {
      int row = 4 * w + rr;
      const float4 hv = *(const float4*)&hs[row][4 * lane];
      const float4 uv = *(const float4*)&upd[row][4 * lane];
      float4 v;
      v.x = hv.x + uv.x; v.y = hv.y + uv.y; v.z = hv.z + uv.z; v.w = hv.w + uv.w;
      *(float4*)&hs[row][4 * lane] = v;
      float s  = v.x + v.y + v.z + v.w;
      float s2 = v.x * v.x + v.y * v.y + v.z * v.z + v.w * v.w;
      #pragma unroll
      for (int off = 32; off; off >>= 1) {
        s  += __shfl_xor(s, off);
        s2 += __shfl_xor(s2, off);
      }
      float mean = s * (1.0f / EE);
      float var = s2 * (1.0f / EE) - mean * mean;
      float rs = rsqrtf(var + 1e-5f);
      const float4 wv = *(const float4*)&lnw[4 * lane];
      const float4 bv = *(const float4*)&lnb[4 * lane];
      ushort4 o;
      o.x = f2bf((v.x - mean) * rs * wv.x + bv.x);
      o.y = f2bf((v.y - mean) * rs * wv.y + bv.y);
      o.z = f2bf((v.z - mean) * rs * wv.z + bv.z);
      o.w = f2bf((v.w - mean) * rs * wv.w + bv.w);
      int sp = (lane >> 1) ^ (row & 7);
      *(ushort4*)&S1[row * 256 + sp * 8 + (lane & 1) * 4] = o;
    }
    __syncthreads();   // ybs + hs(post-attn) complete; upd dead -> R becomes t

    // ---- FFN: two 256-col halves; t half staged in R ----
    f4 acc2[2][2] = {};
    #pragma unroll 1
    for (int H = 0; H < 2; H++) {
      f4 acc1[2][2] = {};
      #pragma unroll
      for (int kstep = 0; kstep < 8; kstep++) {
        short8 af[2], bf_[2];
        #pragma unroll
        for (int mi = 0; mi < 2; mi++) {
          int row = mi * 16 + c;
          int sp = (kstep * 4 + g) ^ (row & 7);
          af[mi] = *(const short8*)&S1[row * 256 + sp * 8];
        }
        #pragma unroll
        for (int ni = 0; ni < 2; ni++) {
          int col = H * 256 + w * 32 + ni * 16 + c;
          bf_[ni] = *(const short8*)(w1b + (size_t)col * EE + kstep * 32 + 8 * g);
        }
        #pragma unroll
        for (int mi = 0; mi < 2; mi++)
          #pragma unroll
          for (int ni = 0; ni < 2; ni++)
            acc1[mi][ni] = __builtin_amdgcn_mfma_f32_16x16x32_bf16(af[mi], bf_[ni], acc1[mi][ni], 0, 0, 0);
      }
      // GELU -> t (bf16, swizzled)
      #pragma unroll
      for (int mi = 0; mi < 2; mi++) {
        #pragma unroll
        for (int ni = 0; ni < 2; ni++) {
          #pragma unroll
          for (int r = 0; r < 4; r++) {
            int row = mi * 16 + 4 * g + r;
            int colH = w * 32 + ni * 16 + c;
            float v = acc1[mi][ni][r] + fb1[H * 256 + colH];
            float gl = 0.5f * v * (1.0f + erff(v * 0.70710678118654752f));
            int sp = (colH >> 3) ^ (row & 7);
            tt[row * 256 + sp * 8 + (colH & 7)] = f2bf(gl);
          }
        }
      }
      __syncthreads();   // t(H) ready
      #pragma unroll
      for (int kstep = 0; kstep < 8; kstep++) {
        short8 af[2], bf_[2];
        #pragma unroll
        for (int mi = 0; mi < 2; mi++) {
          int row = mi * 16 + c;
          int sp = (kstep * 4 + g) ^ (row & 7);
          af[mi] = *(const short8*)&tt[row * 256 + sp * 8];
        }
        #pragma unroll
        for (int ni = 0; ni < 2; ni++) {
          int col = w * 32 + ni * 16 + c;
          bf_[ni] = *(const short8*)(w2b + (size_t)col * 512 + H * 256 + kstep * 32 + 8 * g);
        }
        #pragma unroll
        for (int mi = 0; mi < 2; mi++)
          #pragma unroll
          for (int ni = 0; ni < 2; ni++)
            acc2[mi][ni] = __builtin_amdgcn_mfma_f32_16x16x32_bf16(af[mi], bf_[ni], acc2[mi][ni], 0, 0, 0);
      }
      __syncthreads();   // t reads done (safe to overwrite next half)
    }
    // FFN residual into hs (each lane owns unique (row,col))
    #pragma unroll
    for (int mi = 0; mi < 2; mi++) {
      #pragma unroll
      for (int ni = 0; ni < 2; ni++) {
        #pragma unroll
        for (int r = 0; r < 4; r++) {
          int row = mi * 16 + 4 * g + r;
          int col = w * 32 + ni * 16 + c;
          float v = acc2[mi][ni][r] + fb2[col];
          hs[row][col] += gamma_ffn[col] * v;
        }
      }
    }
    __syncthreads();   // hs final for this layer

    // ---- refresh hsb for next layer's Q-proj ----
    if (layer == 0) {
      #pragma unroll
      for (int i = 0; i < 4; i++) {
        int j = tid + i * 512;
        int row = j >> 6;
        int col = (j & 63) * 4;
        const float4 v = *(const float4*)&hs[row][col];
        ushort4 o;
        o.x = f2bf(v.x); o.y = f2bf(v.y); o.z = f2bf(v.z); o.w = f2bf(v.w);
        int sp = (col >> 3) ^ (row & 7);
        *(ushort4*)&S1[row * 256 + sp * 8 + (col & 7)] = o;
      }
      __syncthreads();
    }
  }

  // ---- correction head: LN -> GEMM(+b1, GELU) -> dot w2 -> out ----
  #pragma unroll
  for (int rr = 0; rr < 4; rr++) {
    int row = 4 * w + rr;
    const float4 v = *(const float4*)&hs[row][4 * lane];
    float s  = v.x + v.y + v.z + v.w;
    float s2 = v.x * v.x + v.y * v.y + v.z * v.z + v.w * v.w;
    #pragma unroll
    for (int off = 32; off; off >>= 1) {
      s  += __shfl_xor(s, off);
      s2 += __shfl_xor(s2, off);
    }
    float mean = s * (1.0f / EE);
    float var = s2 * (1.0f / EE) - mean * mean;
    float rs = rsqrtf(var + 1e-5f);
    const float4 wv = *(const float4*)&clnw[4 * lane];
    const float4 bv = *(const float4*)&clnb[4 * lane];
    ushort4 o;
    o.x = f2bf((v.x - mean) * rs * wv.x + bv.x);
    o.y = f2bf((v.y - mean) * rs * wv.y + bv.y);
    o.z = f2bf((v.z - mean) * rs * wv.z + bv.z);
    o.w = f2bf((v.w - mean) * rs * wv.w + bv.w);
    int sp = (lane >> 1) ^ (row & 7);
    *(ushort4*)&S1[row * 256 + sp * 8 + (lane & 1) * 4] = o;
  }
  __syncthreads();

  f4 acc[2][2] = {};
  #pragma unroll
  for (int kstep = 0; kstep < 8; kstep++) {
    short8 af[2], bf_[2];
    #pragma unroll
    for (int mi = 0; mi < 2; mi++) {
      int row = mi * 16 + c;
      int sp = (kstep * 4 + g) ^ (row & 7);
      af[mi] = *(const short8*)&S1[row * 256 + sp * 8];
    }
    #pragma unroll
    for (int ni = 0; ni < 2; ni++) {
      int col = w * 32 + ni * 16 + c;
      bf_[ni] = *(const short8*)(cw1b + (size_t)col * EE + kstep * 32 + 8 * g);
    }
    #pragma unroll
    for (int mi = 0; mi < 2; mi++)
      #pragma unroll
      for (int ni = 0; ni < 2; ni++)
        acc[mi][ni] = __builtin_amdgcn_mfma_f32_16x16x32_bf16(af[mi], bf_[ni], acc[mi][ni], 0, 0, 0);
  }
  float b1v[2], w2v[2];
  #pragma unroll
  for (int ni = 0; ni < 2; ni++) {
    int col = w * 32 + ni * 16 + c;
    b1v[ni] = cb1[col];
    w2v[ni] = cw2[col];
  }
  __syncthreads();   // S1 GEMM reads done block-wide before red overlays R (R already free)
  #pragma unroll
  for (int mi = 0; mi < 2; mi++) {
    #pragma unroll
    for (int r = 0; r < 4; r++) {
      float s = 0.f;
      #pragma unroll
      for (int ni = 0; ni < 2; ni++) {
        float v = acc[mi][ni][r] + b1v[ni];
        float gl = 0.5f * v * (1.0f + erff(v * 0.70710678118654752f));
        s += gl * w2v[ni];
      }
      s += __shfl_xor(s, 1);
      s += __shfl_xor(s, 2);
      s += __shfl_xor(s, 4);
      s += __shfl_xor(s, 8);
      if (c == 0) red[w][mi * 16 + 4 * g + r] = s;
    }
  }
  __syncthreads();
  if (tid < 32) {
    float s = 0.f;
    #pragma unroll
    for (int ww = 0; ww < 8; ww++) s += red[ww][tid];
    out[(b << 10) + q0 + tid] = s + cb2[0];
  }
}

extern "C" void kernel_launch(void* const* d_in, const int* in_sizes, int n_in,
                              void* d_out, int out_size, void* d_ws, size_t ws_size,
                              hipStream_t stream) {
  const float* x            = (const float*)d_in[0];
  const float* value_w      = (const float*)d_in[1];
  const float* value_b      = (const float*)d_in[2];
  const float* feature_embed= (const float*)d_in[3];
  const float* binary_w     = (const float*)d_in[4];
  const float* qw           = (const float*)d_in[5];
  const float* kw           = (const float*)d_in[6];
  const float* vw           = (const float*)d_in[7];
  const float* film_alpha   = (const float*)d_in[8];
  const float* film_a       = (const float*)d_in[9];
  const float* ln1_w        = (const float*)d_in[10];
  const float* ln1_b        = (const float*)d_in[11];
  const float* ffn_w1       = (const float*)d_in[12];
  const float* ffn_b1       = (const float*)d_in[13];
  const float* ffn_w2       = (const float*)d_in[14];
  const float* ffn_b2       = (const float*)d_in[15];
  const float* gamma_attn   = (const float*)d_in[16];
  const float* gamma_ffn    = (const float*)d_in[17];
  const float* corr_ln_w    = (const float*)d_in[18];
  const float* corr_ln_b    = (const float*)d_in[19];
  const float* corr_w1      = (const float*)d_in[20];
  const float* corr_b1      = (const float*)d_in[21];
  const float* corr_w2      = (const float*)d_in[22];
  const float* corr_b2      = (const float*)d_in[23];
  const float* alibi_strength=(const float*)d_in[24];

  const size_t ME = (size_t)BD * DD * EE;   // 2M
  float* ws = (float*)d_ws;
  float* qscale = ws;                       // 8192 f
  float* hb     = qscale + BD * DD;         // 2M f
  ushort* kv_bf = (ushort*)(hb + ME);       // 2M us
  ushort* Kbf   = kv_bf + ME;               // 2M us
  ushort* Vtb   = Kbf + ME;                 // 2M us
  ushort* wbf   = Vtb + ME;                 // 524288 us
  ushort* qwb   = wbf;
  ushort* kwb   = wbf + 65536;              // kw rows 0-255, vw rows 256-511 (contiguous)
  ushort* w1b   = wbf + 196608;
  ushort* w2b   = wbf + 327680;
  ushort* cw1b  = wbf + 458752;

  const int M = BD * DD;   // 8192

  k_pro<<<8192 + 8 + 2048, 256, 0, stream>>>(x, value_w, value_b, feature_embed, binary_w,
                                             kv_bf, hb,
                                             film_alpha, film_a, qscale,
                                             qw, kw, vw, ffn_w1, ffn_w2, corr_w1, wbf);

  kvgemm_k<256><<<dim3(512 / 64, M / 128), 512, 0, stream>>>(kv_bf, kwb, Kbf, Vtb);

  mega_k<<<dim3(256), 512, 0, stream>>>(hb, qwb, qscale, Kbf, Vtb,
                                        gamma_attn, alibi_strength,
                                        ln1_w, ln1_b,
                                        w1b, ffn_b1, w2b, ffn_b2, gamma_ffn,
                                        corr_ln_w, corr_ln_b,
                                        cw1b, corr_b1, corr_w2, corr_b2,
                                        (float*)d_out);
}